// Round 1
// baseline (8627.551 us; speedup 1.0000x reference)
//
#include <hip/hip_runtime.h>
#include <hip/hip_bf16.h>

// Problem constants
#define BB 2
#define SS 2048
#define DD 1024
#define HH 16
#define HDD 64
// tokens = BB*SS = 4096

// ---------------------------------------------------------------------------
// Generic fp32 GEMM: C[M,N] = A[M,K] @ W[K,N] + bias[N]
// A row-major, W row-major, no bounds checks (M%64==0, N%64==0, K%16==0).
// BM=BN=64, BK=16, 256 threads, 4x4 microtile per thread.
// ---------------------------------------------------------------------------
__global__ __launch_bounds__(256) void gemm_bias_kernel(
    const float* __restrict__ A, const float* __restrict__ W,
    const float* __restrict__ bias, float* __restrict__ C,
    int M, int N, int K)
{
    __shared__ float As[16][68];   // +4 pad: aligned float4 rows, conflict-free
    __shared__ float Bs[16][64];

    const int tid = threadIdx.x;
    const int tx = tid % 16;       // n microtile index (cols tx*4..+3)
    const int ty = tid / 16;       // m microtile index (rows ty*4..+3)
    const int bm = blockIdx.x * 64;
    const int bn = blockIdx.y * 64;

    float acc[4][4] = {};

    const int ac = tid % 16, ar = tid / 16;  // A loader: col=k, rows +16 apart
    const int bc = tid % 64, br = tid / 64;  // W loader: col=n, rows +4 apart

    for (int k0 = 0; k0 < K; k0 += 16) {
        #pragma unroll
        for (int i = 0; i < 4; i++)
            As[ac][ar + 16 * i] = A[(size_t)(bm + ar + 16 * i) * K + k0 + ac];
        #pragma unroll
        for (int i = 0; i < 4; i++)
            Bs[br + 4 * i][bc] = W[(size_t)(k0 + br + 4 * i) * N + bn + bc];
        __syncthreads();

        #pragma unroll
        for (int kk = 0; kk < 16; kk++) {
            float4 a4 = *reinterpret_cast<const float4*>(&As[kk][ty * 4]);
            float4 b4 = *reinterpret_cast<const float4*>(&Bs[kk][tx * 4]);
            float av[4] = {a4.x, a4.y, a4.z, a4.w};
            float bv[4] = {b4.x, b4.y, b4.z, b4.w};
            #pragma unroll
            for (int i = 0; i < 4; i++)
                #pragma unroll
                for (int j = 0; j < 4; j++)
                    acc[i][j] += av[i] * bv[j];
        }
        __syncthreads();
    }

    #pragma unroll
    for (int i = 0; i < 4; i++) {
        const int row = bm + ty * 4 + i;
        const int col = bn + tx * 4;
        float4 o;
        o.x = acc[i][0] + bias[col + 0];
        o.y = acc[i][1] + bias[col + 1];
        o.z = acc[i][2] + bias[col + 2];
        o.w = acc[i][3] + bias[col + 3];
        *reinterpret_cast<float4*>(&C[(size_t)row * N + col]) = o;
    }
}

// ---------------------------------------------------------------------------
// Flash attention, one wave per query row; lane = head-dim element (HD==64).
// Online softmax over S keys, then fused "exclusive" postprocess:
//   y = y - (y . v_norm) v_norm,  v_norm = v[b,q,h,:]/||v||
// q,k,v layout: [B,S,H,HD] fp32 (as produced by the QKV GEMMs).
// ---------------------------------------------------------------------------
__global__ __launch_bounds__(256) void attn_kernel(
    const float* __restrict__ qb, const float* __restrict__ kb,
    const float* __restrict__ vb, float* __restrict__ yb)
{
    const int wid = threadIdx.x >> 6;
    const int lane = threadIdx.x & 63;
    const int r = blockIdx.x * 4 + wid;       // r in [0, B*H*S)
    const int b = r / (HH * SS);
    const int h = (r / SS) % HH;
    const int q = r % SS;

    const float scale = 0.125f;               // 1/sqrt(64)
    const size_t head_base = ((size_t)b * SS) * (HH * HDD) + (size_t)h * HDD;
    const float* kp = kb + head_base;
    const float* vp = vb + head_base;

    const float qv = qb[head_base + (size_t)q * (HH * HDD) + lane] * scale;

    float m = -1e30f, l = 0.0f, o = 0.0f;
    for (int s = 0; s < SS; s++) {
        const size_t off = (size_t)s * (HH * HDD) + lane;
        float prod = qv * kp[off];
        #pragma unroll
        for (int d = 32; d; d >>= 1) prod += __shfl_xor(prod, d);
        const float mn = fmaxf(m, prod);
        const float corr = __expf(m - mn);
        const float p = __expf(prod - mn);
        l = l * corr + p;
        o = o * corr + p * vp[off];
        m = mn;
    }
    o /= l;

    // exclusive postprocess: remove projection onto normalized v at (b,q,h)
    const float vq = vp[(size_t)q * (HH * HDD) + lane];
    float vv = vq * vq;
    #pragma unroll
    for (int d = 32; d; d >>= 1) vv += __shfl_xor(vv, d);
    const float rs = rsqrtf(vv + 1e-12f);
    const float vn = vq * rs;
    float dv = o * vn;
    #pragma unroll
    for (int d = 32; d; d >>= 1) dv += __shfl_xor(dv, d);
    o -= dv * vn;

    yb[head_base + (size_t)q * (HH * HDD) + lane] = o;
}

// ---------------------------------------------------------------------------
// Launch
// ---------------------------------------------------------------------------
extern "C" void kernel_launch(void* const* d_in, const int* in_sizes, int n_in,
                              void* d_out, int out_size, void* d_ws, size_t ws_size,
                              hipStream_t stream)
{
    const float* x  = (const float*)d_in[0];
    const float* Wq = (const float*)d_in[1];
    const float* bq = (const float*)d_in[2];
    const float* Wk = (const float*)d_in[3];
    const float* bk = (const float*)d_in[4];
    const float* Wv = (const float*)d_in[5];
    const float* bv = (const float*)d_in[6];
    const float* Wo = (const float*)d_in[7];
    const float* bo = (const float*)d_in[8];
    float* out = (float*)d_out;

    // Workspace: q, k, v, y each B*S*H*HD = 4,194,304 floats (total 64 MiB)
    float* ws = (float*)d_ws;
    float* qw = ws;
    float* kw = ws + 4194304;
    float* vw = ws + 8388608;
    float* yw = ws + 12582912;

    const int M = BB * SS;   // 4096
    const int N = DD;        // 1024 (= H*HD)
    const int K = DD;        // 1024

    dim3 blk(256);
    dim3 gg(M / 64, N / 64);

    // QKV projections: Wq/Wk/Wv are [D,H,HD] = row-major [1024,1024]
    gemm_bias_kernel<<<gg, blk, 0, stream>>>(x, Wq, bq, qw, M, N, K);
    gemm_bias_kernel<<<gg, blk, 0, stream>>>(x, Wk, bk, kw, M, N, K);
    gemm_bias_kernel<<<gg, blk, 0, stream>>>(x, Wv, bv, vw, M, N, K);

    // Attention + fused exclusive postprocess
    const int rows = BB * HH * SS;           // 65536 query rows
    attn_kernel<<<rows / 4, blk, 0, stream>>>(qw, kw, vw, yw);

    // Output projection: Wo is [H,HD,D] = row-major [1024,1024]
    gemm_bias_kernel<<<gg, blk, 0, stream>>>(yw, Wo, bo, out, M, N, K);
}

// Round 2
// 836.638 us; speedup vs baseline: 10.3122x; 10.3122x over previous
//
#include <hip/hip_runtime.h>

#define BB 2
#define SS 2048
#define DD 1024
#define HH 16
#define HDD 64

typedef __attribute__((ext_vector_type(4))) float f32x4;
typedef __attribute__((ext_vector_type(8))) short short8;
typedef __attribute__((ext_vector_type(4))) short short4v;

__device__ __forceinline__ short f2bf(float f) {
    union { float f; unsigned u; } a; a.f = f;
    unsigned r = a.u + 0x7fffu + ((a.u >> 16) & 1u);
    return (short)(r >> 16);
}

// ---------------------------------------------------------------------------
// fp32 GEMM: C[M,N] = A[M,K] @ W[K,N] + bias[N], then mode-specific epilogue:
//  MODE 0: bf16 out [B,H,S,64], value=(acc+bias)*scale   (Q, scale=0.125*log2e)
//  MODE 1: bf16 out [B,H,S,64]                           (K)
//  MODE 2: fp32 [B,S,H,64] + bf16 transposed [B,H,64,S]  (V)
//  MODE 3: fp32 row-major [M,N] + bias                   (final out-proj)
// ---------------------------------------------------------------------------
template<int MODE>
__global__ __launch_bounds__(256) void gemm_bias_kernel(
    const float* __restrict__ A, const float* __restrict__ W,
    const float* __restrict__ bias, float* __restrict__ outF,
    short* __restrict__ outB, float scale,
    int M, int N, int K)
{
    __shared__ float As[16][68];
    __shared__ float Bs[16][64];

    const int tid = threadIdx.x;
    const int tx = tid % 16;
    const int ty = tid / 16;
    const int bm = blockIdx.x * 64;
    const int bn = blockIdx.y * 64;

    float acc[4][4] = {};

    const int ac = tid % 16, ar = tid / 16;
    const int bc = tid % 64, br = tid / 64;

    for (int k0 = 0; k0 < K; k0 += 16) {
        #pragma unroll
        for (int i = 0; i < 4; i++)
            As[ac][ar + 16 * i] = A[(size_t)(bm + ar + 16 * i) * K + k0 + ac];
        #pragma unroll
        for (int i = 0; i < 4; i++)
            Bs[br + 4 * i][bc] = W[(size_t)(k0 + br + 4 * i) * N + bn + bc];
        __syncthreads();

        #pragma unroll
        for (int kk = 0; kk < 16; kk++) {
            float4 a4 = *reinterpret_cast<const float4*>(&As[kk][ty * 4]);
            float4 b4 = *reinterpret_cast<const float4*>(&Bs[kk][tx * 4]);
            float av[4] = {a4.x, a4.y, a4.z, a4.w};
            float bv[4] = {b4.x, b4.y, b4.z, b4.w};
            #pragma unroll
            for (int i = 0; i < 4; i++)
                #pragma unroll
                for (int j = 0; j < 4; j++)
                    acc[i][j] += av[i] * bv[j];
        }
        __syncthreads();
    }

    const int h = blockIdx.y;          // modes 0..2: one N-block == one head
    const int col = bn + tx * 4;

    #pragma unroll
    for (int i = 0; i < 4; i++) {
        const int t = bm + ty * 4 + i;
        float r0 = (acc[i][0] + bias[col + 0]) * scale;
        float r1 = (acc[i][1] + bias[col + 1]) * scale;
        float r2 = (acc[i][2] + bias[col + 2]) * scale;
        float r3 = (acc[i][3] + bias[col + 3]) * scale;
        if constexpr (MODE == 0 || MODE == 1) {
            const int b = t >> 11, s = t & 2047;
            size_t ad = ((size_t)(b * HH + h) * SS + s) * HDD + tx * 4;
            short4v pk = { f2bf(r0), f2bf(r1), f2bf(r2), f2bf(r3) };
            *(short4v*)(outB + ad) = pk;
        } else if constexpr (MODE == 2) {
            const int b = t >> 11, s = t & 2047;
            size_t ad = ((size_t)(b * SS + s) * HH + h) * HDD + tx * 4;
            f32x4 o = { r0, r1, r2, r3 };
            *(f32x4*)(outF + ad) = o;
        } else {
            f32x4 o = { r0, r1, r2, r3 };
            *(f32x4*)(&outF[(size_t)t * N + col]) = o;
        }
    }
    if constexpr (MODE == 2) {
        // Vt[b, h, d, s] bf16
        const int t0 = bm + ty * 4;
        const int b = t0 >> 11, sl = t0 & 2047;
        #pragma unroll
        for (int j = 0; j < 4; j++) {
            const int d = tx * 4 + j;
            const float bj = bias[col + j];
            short4v pk = { f2bf(acc[0][j] + bj), f2bf(acc[1][j] + bj),
                           f2bf(acc[2][j] + bj), f2bf(acc[3][j] + bj) };
            *(short4v*)(outB + ((size_t)(b * HH + h) * HDD + d) * SS + sl) = pk;
        }
    }
}

// ---------------------------------------------------------------------------
// MFMA flash attention + fused exclusive postprocess.
// 1 wave = 16 query rows; 32-key tiles; swapped QK^T (scores [key][q]);
// PV via consistent k-permutation on both operands (no shuffles).
// ---------------------------------------------------------------------------
__global__ __launch_bounds__(256) void attn_mfma_kernel(
    const short* __restrict__ Qh, const short* __restrict__ Kh,
    const short* __restrict__ Vt, const float* __restrict__ vw,
    float* __restrict__ yw)
{
    const int lane = threadIdx.x & 63;
    const int wid  = threadIdx.x >> 6;
    const int ln15 = lane & 15;
    const int g    = lane >> 4;

    const int bid  = blockIdx.x;
    const int bh   = bid >> 5;                 // b*16 + h
    const int q0   = (bid & 31) * 64 + wid * 16;

    const short* qbase = Qh + (size_t)bh * SS * HDD;
    const short* kbase = Kh + (size_t)bh * SS * HDD;
    const short* vtb   = Vt + (size_t)bh * HDD * SS;

    const short8 qf0 = *(const short8*)(qbase + (size_t)(q0 + ln15) * HDD + g * 8);
    const short8 qf1 = *(const short8*)(qbase + (size_t)(q0 + ln15) * HDD + 32 + g * 8);

    f32x4 o[4];
    #pragma unroll
    for (int c = 0; c < 4; c++) o[c] = (f32x4){0.f, 0.f, 0.f, 0.f};
    float m = -1e30f, l = 0.f;

    for (int s0 = 0; s0 < SS; s0 += 32) {
        const short* kr = kbase + (size_t)(s0 + ln15) * HDD + g * 8;
        short8 kf00 = *(const short8*)(kr);
        short8 kf01 = *(const short8*)(kr + 32);
        short8 kf10 = *(const short8*)(kr + 16 * HDD);
        short8 kf11 = *(const short8*)(kr + 16 * HDD + 32);

        const f32x4 z = {0.f, 0.f, 0.f, 0.f};
        f32x4 sA = __builtin_amdgcn_mfma_f32_16x16x32_bf16(kf00, qf0, z, 0, 0, 0);
        sA = __builtin_amdgcn_mfma_f32_16x16x32_bf16(kf01, qf1, sA, 0, 0, 0);
        f32x4 sB = __builtin_amdgcn_mfma_f32_16x16x32_bf16(kf10, qf0, z, 0, 0, 0);
        sB = __builtin_amdgcn_mfma_f32_16x16x32_bf16(kf11, qf1, sB, 0, 0, 0);

        float pm = fmaxf(fmaxf(fmaxf(sA[0], sA[1]), fmaxf(sA[2], sA[3])),
                         fmaxf(fmaxf(sB[0], sB[1]), fmaxf(sB[2], sB[3])));
        pm = fmaxf(pm, __shfl_xor(pm, 16));
        pm = fmaxf(pm, __shfl_xor(pm, 32));
        const float mn = fmaxf(m, pm);
        const float corr = exp2f(m - mn);

        float p0[4], p1[4], ps = 0.f;
        #pragma unroll
        for (int r = 0; r < 4; r++) {
            p0[r] = exp2f(sA[r] - mn);
            p1[r] = exp2f(sB[r] - mn);
            ps += p0[r] + p1[r];
        }
        ps += __shfl_xor(ps, 16);
        ps += __shfl_xor(ps, 32);
        l = l * corr + ps;
        m = mn;

        #pragma unroll
        for (int c = 0; c < 4; c++) o[c] *= corr;

        short8 pf;
        #pragma unroll
        for (int r = 0; r < 4; r++) { pf[r] = f2bf(p0[r]); pf[r + 4] = f2bf(p1[r]); }

        #pragma unroll
        for (int c = 0; c < 4; c++) {
            const short* vr = vtb + (size_t)(c * 16 + ln15) * SS + s0 + 4 * g;
            short4v lo = *(const short4v*)(vr);
            short4v hi = *(const short4v*)(vr + 16);
            short8 vf;
            #pragma unroll
            for (int e = 0; e < 4; e++) { vf[e] = lo[e]; vf[e + 4] = hi[e]; }
            o[c] = __builtin_amdgcn_mfma_f32_16x16x32_bf16(vf, pf, o[c], 0, 0, 0);
        }
    }

    const float inv = 1.f / l;
    #pragma unroll
    for (int c = 0; c < 4; c++) o[c] *= inv;

    // exclusive postprocess in fp32: y -= (y . v_norm) v_norm
    const int b = bh >> 4, h = bh & 15;
    const float* vp = vw + ((size_t)(b * SS + q0 + ln15) * HH + h) * HDD;
    float* yp = yw + ((size_t)(b * SS + q0 + ln15) * HH + h) * HDD;
    f32x4 v4[4];
    float nv = 0.f, dv = 0.f;
    #pragma unroll
    for (int c = 0; c < 4; c++) {
        v4[c] = *(const f32x4*)(vp + c * 16 + 4 * g);
        #pragma unroll
        for (int r = 0; r < 4; r++) {
            nv += v4[c][r] * v4[c][r];
            dv += o[c][r] * v4[c][r];
        }
    }
    nv += __shfl_xor(nv, 16); nv += __shfl_xor(nv, 32);
    dv += __shfl_xor(dv, 16); dv += __shfl_xor(dv, 32);
    const float t = dv / (nv + 1e-12f);
    #pragma unroll
    for (int c = 0; c < 4; c++) {
        f32x4 yo = o[c] - v4[c] * t;
        *(f32x4*)(yp + c * 16 + 4 * g) = yo;
    }
}

// ---------------------------------------------------------------------------
// Launch
// ---------------------------------------------------------------------------
extern "C" void kernel_launch(void* const* d_in, const int* in_sizes, int n_in,
                              void* d_out, int out_size, void* d_ws, size_t ws_size,
                              hipStream_t stream)
{
    const float* x  = (const float*)d_in[0];
    const float* Wq = (const float*)d_in[1];
    const float* bq = (const float*)d_in[2];
    const float* Wk = (const float*)d_in[3];
    const float* bk = (const float*)d_in[4];
    const float* Wv = (const float*)d_in[5];
    const float* bv = (const float*)d_in[6];
    const float* Wo = (const float*)d_in[7];
    const float* bo = (const float*)d_in[8];
    float* out = (float*)d_out;

    // ws layout (56 MiB): Qh 8M | Kh 8M | Vt 8M | vw 16M | yw 16M
    char* w = (char*)d_ws;
    short* Qh = (short*)(w);
    short* Kh = (short*)(w + (8ull << 20));
    short* Vt = (short*)(w + (16ull << 20));
    float* vw = (float*)(w + (24ull << 20));
    float* yw = (float*)(w + (40ull << 20));

    const int M = BB * SS, N = DD, K = DD;
    dim3 blk(256);
    dim3 gg(M / 64, N / 64);
    const float qscale = 0.125f * 1.44269504f;   // 1/sqrt(HD) * log2(e)

    gemm_bias_kernel<0><<<gg, blk, 0, stream>>>(x, Wq, bq, nullptr, Qh, qscale, M, N, K);
    gemm_bias_kernel<1><<<gg, blk, 0, stream>>>(x, Wk, bk, nullptr, Kh, 1.f, M, N, K);
    gemm_bias_kernel<2><<<gg, blk, 0, stream>>>(x, Wv, bv, vw, Vt, 1.f, M, N, K);

    attn_mfma_kernel<<<dim3(BB * HH * SS / 64), blk, 0, stream>>>(Qh, Kh, Vt, vw, yw);

    gemm_bias_kernel<3><<<gg, blk, 0, stream>>>(yw, Wo, bo, out, nullptr, 1.f, M, N, K);
}

// Round 3
// 430.022 us; speedup vs baseline: 20.0630x; 1.9456x over previous
//
#include <hip/hip_runtime.h>

#define BB 2
#define SS 2048
#define DD 1024
#define HH 16
#define HDD 64

typedef __attribute__((ext_vector_type(4))) float f32x4;
typedef __attribute__((ext_vector_type(8))) short short8;
typedef __attribute__((ext_vector_type(4))) short short4v;

__device__ __forceinline__ short f2bf(float f) {
    union { float f; unsigned u; } a; a.f = f;
    unsigned r = a.u + 0x7fffu + ((a.u >> 16) & 1u);
    return (short)(r >> 16);
}
__device__ __forceinline__ float bf2f(short s) {
    union { unsigned u; float f; } a; a.u = ((unsigned)(unsigned short)s) << 16;
    return a.f;
}

// ---------------------------------------------------------------------------
// Converts
// ---------------------------------------------------------------------------
__global__ __launch_bounds__(256) void conv_x(const float* __restrict__ src,
                                              short* __restrict__ dst)
{
    const int i = (blockIdx.x * 256 + threadIdx.x) * 8;
    f32x4 a = *(const f32x4*)(src + i);
    f32x4 b = *(const f32x4*)(src + i + 4);
    short8 o;
    #pragma unroll
    for (int j = 0; j < 4; j++) { o[j] = f2bf(a[j]); o[j + 4] = f2bf(b[j]); }
    *(short8*)(dst + i) = o;
}

// src fp32 [1024 k][1024 n] -> dst bf16 [1024 n][1024 k], scaled
__global__ __launch_bounds__(256) void conv_wT(const float* __restrict__ src,
                                               short* __restrict__ dst, float scale)
{
    __shared__ float t[64][65];
    const int tid = threadIdx.x;
    const int c = tid & 63, rg = tid >> 6;
    const int bi = blockIdx.x * 64, bj = blockIdx.y * 64;
    #pragma unroll
    for (int i = 0; i < 16; i++)
        t[rg * 16 + i][c] = src[(size_t)(bi + rg * 16 + i) * 1024 + bj + c];
    __syncthreads();
    #pragma unroll
    for (int i = 0; i < 16; i++)
        dst[(size_t)(bj + rg * 16 + i) * 1024 + bi + c] = f2bf(scale * t[c][rg * 16 + i]);
}

__global__ __launch_bounds__(256) void conv_bias(const float* __restrict__ bq,
                                                 const float* __restrict__ bk,
                                                 const float* __restrict__ bv,
                                                 float* __restrict__ bcat, float qscale)
{
    const int i = blockIdx.x * 256 + threadIdx.x;   // grid 12 -> 3072
    float v = (i < 1024) ? bq[i] * qscale : (i < 2048 ? bk[i - 1024] : bv[i - 2048]);
    bcat[i] = v;
}

// ---------------------------------------------------------------------------
// bf16 MFMA GEMM: C[M,N] = A[M,K] @ Bt[N,K]^T + bias, K=1024.
// 128x128 tile, BK=64, 4 waves (2x2), wave tile 64x64 = 4x4 16x16x32 frags.
// LDS XOR-swizzled (cc^(r&7)) on write & read -> conflict-free ds_read_b128.
// MODE 0: swapped-operand acc (lane holds 4 consecutive n) -> Q/K bf16
//         [B,H,S,64] stores (short4 along d). Outputs split at n=1024.
// MODE 1: normal acc (lane holds 4 consecutive m=s) -> Vt bf16 [B,H,64,S].
// MODE 2: swapped -> fp32 out[M,1024] + bias, f32x4 stores.
// ---------------------------------------------------------------------------
template<int MODE>
__global__ __launch_bounds__(256) void gemm_mfma(
    const short* __restrict__ A, const short* __restrict__ Bt,
    const float* __restrict__ bias,
    short* __restrict__ o0, short* __restrict__ o1, float* __restrict__ of)
{
    __shared__ short lds[16384];          // As 16KB | Bs 16KB
    const int tid = threadIdx.x;
    const int lane = tid & 63;
    const int ln15 = lane & 15;
    const int g = lane >> 4;
    const int wid = tid >> 6;
    const int wm = wid >> 1, wn = wid & 1;
    const int bm = blockIdx.x * 128;
    const int bn = blockIdx.y * 128;

    f32x4 acc[4][4];
    #pragma unroll
    for (int i = 0; i < 4; i++)
        #pragma unroll
        for (int j = 0; j < 4; j++) acc[i][j] = (f32x4){0.f, 0.f, 0.f, 0.f};

    const int r_s = tid >> 3;             // staging row base (0..31)
    const int cc_s = tid & 7;             // staging chunk col

    for (int k0 = 0; k0 < 1024; k0 += 64) {
        __syncthreads();
        #pragma unroll
        for (int i = 0; i < 4; i++) {
            const int r = r_s + i * 32;
            short8 v = *(const short8*)(A + (size_t)(bm + r) * 1024 + k0 + cc_s * 8);
            *(short8*)((char*)lds + r * 128 + ((cc_s ^ (r & 7)) << 4)) = v;
        }
        #pragma unroll
        for (int i = 0; i < 4; i++) {
            const int r = r_s + i * 32;
            short8 v = *(const short8*)(Bt + (size_t)(bn + r) * 1024 + k0 + cc_s * 8);
            *(short8*)((char*)lds + 16384 + r * 128 + ((cc_s ^ (r & 7)) << 4)) = v;
        }
        __syncthreads();

        #pragma unroll
        for (int kk = 0; kk < 2; kk++) {
            short8 af[4], bf[4];
            #pragma unroll
            for (int f = 0; f < 4; f++) {
                const int ra = wm * 64 + f * 16 + ln15;
                af[f] = *(const short8*)((char*)lds + ra * 128 +
                                         ((((kk << 2) | g) ^ (ra & 7)) << 4));
                const int rb = wn * 64 + f * 16 + ln15;
                bf[f] = *(const short8*)((char*)lds + 16384 + rb * 128 +
                                         ((((kk << 2) | g) ^ (rb & 7)) << 4));
            }
            #pragma unroll
            for (int fm = 0; fm < 4; fm++)
                #pragma unroll
                for (int fn = 0; fn < 4; fn++) {
                    if constexpr (MODE == 1)
                        acc[fm][fn] = __builtin_amdgcn_mfma_f32_16x16x32_bf16(
                            af[fm], bf[fn], acc[fm][fn], 0, 0, 0);
                    else
                        acc[fm][fn] = __builtin_amdgcn_mfma_f32_16x16x32_bf16(
                            bf[fn], af[fm], acc[fm][fn], 0, 0, 0);
                }
        }
    }

    const int n_base = bn + wn * 64;

    if constexpr (MODE == 0) {
        short* dst = (n_base < 1024) ? o0 : o1;       // Q or K (wave-uniform)
        #pragma unroll
        for (int fn = 0; fn < 4; fn++) {
            const int n0 = n_base + fn * 16 + 4 * g;
            const f32x4 b4 = *(const f32x4*)(bias + n0);
            const int nl = n0 & 1023;
            const int h = nl >> 6, d = nl & 63;
            #pragma unroll
            for (int fm = 0; fm < 4; fm++) {
                const int t = bm + wm * 64 + fm * 16 + ln15;
                const int b = t >> 11, s = t & 2047;
                short4v pk = { f2bf(acc[fm][fn][0] + b4[0]), f2bf(acc[fm][fn][1] + b4[1]),
                               f2bf(acc[fm][fn][2] + b4[2]), f2bf(acc[fm][fn][3] + b4[3]) };
                *(short4v*)(dst + ((size_t)(b * HH + h) * SS + s) * HDD + d) = pk;
            }
        }
    } else if constexpr (MODE == 1) {
        #pragma unroll
        for (int fn = 0; fn < 4; fn++) {
            const int nl = n_base + fn * 16 + ln15;   // 0..1023 (V-local)
            const float bb = bias[nl];
            const int h = nl >> 6, d = nl & 63;
            #pragma unroll
            for (int fm = 0; fm < 4; fm++) {
                const int t0 = bm + wm * 64 + fm * 16 + 4 * g;
                const int b = t0 >> 11, s0 = t0 & 2047;
                short4v pk = { f2bf(acc[fm][fn][0] + bb), f2bf(acc[fm][fn][1] + bb),
                               f2bf(acc[fm][fn][2] + bb), f2bf(acc[fm][fn][3] + bb) };
                *(short4v*)(o0 + ((size_t)(b * HH + h) * HDD + d) * SS + s0) = pk;
            }
        }
    } else {
        #pragma unroll
        for (int fn = 0; fn < 4; fn++) {
            const int n0 = n_base + fn * 16 + 4 * g;
            const f32x4 b4 = *(const f32x4*)(bias + n0);
            #pragma unroll
            for (int fm = 0; fm < 4; fm++) {
                const int t = bm + wm * 64 + fm * 16 + ln15;
                f32x4 o = acc[fm][fn] + b4;
                *(f32x4*)(of + (size_t)t * 1024 + n0) = o;
            }
        }
    }
}

// ---------------------------------------------------------------------------
// MFMA flash attention + fused exclusive postprocess (v from bf16 Vt).
// Writes y as bf16 [token][1024] for the out-projection GEMM.
// ---------------------------------------------------------------------------
__global__ __launch_bounds__(256) void attn_mfma_kernel(
    const short* __restrict__ Qh, const short* __restrict__ Kh,
    const short* __restrict__ Vt, short* __restrict__ yb)
{
    const int lane = threadIdx.x & 63;
    const int wid  = threadIdx.x >> 6;
    const int ln15 = lane & 15;
    const int g    = lane >> 4;

    const int bid  = blockIdx.x;
    const int bh   = bid >> 5;                 // b*16 + h
    const int q0   = (bid & 31) * 64 + wid * 16;

    const short* qbase = Qh + (size_t)bh * SS * HDD;
    const short* kbase = Kh + (size_t)bh * SS * HDD;
    const short* vtb   = Vt + (size_t)bh * HDD * SS;

    const short8 qf0 = *(const short8*)(qbase + (size_t)(q0 + ln15) * HDD + g * 8);
    const short8 qf1 = *(const short8*)(qbase + (size_t)(q0 + ln15) * HDD + 32 + g * 8);

    f32x4 o[4];
    #pragma unroll
    for (int c = 0; c < 4; c++) o[c] = (f32x4){0.f, 0.f, 0.f, 0.f};
    float m = -1e30f, l = 0.f;

    for (int s0 = 0; s0 < SS; s0 += 32) {
        const short* kr = kbase + (size_t)(s0 + ln15) * HDD + g * 8;
        short8 kf00 = *(const short8*)(kr);
        short8 kf01 = *(const short8*)(kr + 32);
        short8 kf10 = *(const short8*)(kr + 16 * HDD);
        short8 kf11 = *(const short8*)(kr + 16 * HDD + 32);

        const f32x4 z = {0.f, 0.f, 0.f, 0.f};
        __builtin_amdgcn_s_setprio(1);
        f32x4 sA = __builtin_amdgcn_mfma_f32_16x16x32_bf16(kf00, qf0, z, 0, 0, 0);
        sA = __builtin_amdgcn_mfma_f32_16x16x32_bf16(kf01, qf1, sA, 0, 0, 0);
        f32x4 sB = __builtin_amdgcn_mfma_f32_16x16x32_bf16(kf10, qf0, z, 0, 0, 0);
        sB = __builtin_amdgcn_mfma_f32_16x16x32_bf16(kf11, qf1, sB, 0, 0, 0);
        __builtin_amdgcn_s_setprio(0);

        float pm = fmaxf(fmaxf(fmaxf(sA[0], sA[1]), fmaxf(sA[2], sA[3])),
                         fmaxf(fmaxf(sB[0], sB[1]), fmaxf(sB[2], sB[3])));
        pm = fmaxf(pm, __shfl_xor(pm, 16));
        pm = fmaxf(pm, __shfl_xor(pm, 32));
        const float mn = fmaxf(m, pm);
        const float corr = exp2f(m - mn);

        float p0[4], p1[4], ps = 0.f;
        #pragma unroll
        for (int r = 0; r < 4; r++) {
            p0[r] = exp2f(sA[r] - mn);
            p1[r] = exp2f(sB[r] - mn);
            ps += p0[r] + p1[r];
        }
        ps += __shfl_xor(ps, 16);
        ps += __shfl_xor(ps, 32);
        l = l * corr + ps;
        m = mn;

        #pragma unroll
        for (int c = 0; c < 4; c++) o[c] *= corr;

        short8 pf;
        #pragma unroll
        for (int r = 0; r < 4; r++) { pf[r] = f2bf(p0[r]); pf[r + 4] = f2bf(p1[r]); }

        __builtin_amdgcn_s_setprio(1);
        #pragma unroll
        for (int c = 0; c < 4; c++) {
            const short* vr = vtb + (size_t)(c * 16 + ln15) * SS + s0 + 4 * g;
            short4v lo = *(const short4v*)(vr);
            short4v hi = *(const short4v*)(vr + 16);
            short8 vf;
            #pragma unroll
            for (int e = 0; e < 4; e++) { vf[e] = lo[e]; vf[e + 4] = hi[e]; }
            o[c] = __builtin_amdgcn_mfma_f32_16x16x32_bf16(vf, pf, o[c], 0, 0, 0);
        }
        __builtin_amdgcn_s_setprio(0);
    }

    const float inv = 1.f / l;
    #pragma unroll
    for (int c = 0; c < 4; c++) o[c] *= inv;

    // exclusive postprocess: y -= (y . v_norm) v_norm   (v from bf16 Vt)
    float v4[4][4];
    float nv = 0.f, dv = 0.f;
    #pragma unroll
    for (int c = 0; c < 4; c++)
        #pragma unroll
        for (int r = 0; r < 4; r++) {
            const float vd = bf2f(vtb[(size_t)(c * 16 + 4 * g + r) * SS + q0 + ln15]);
            v4[c][r] = vd;
            nv += vd * vd;
            dv += o[c][r] * vd;
        }
    nv += __shfl_xor(nv, 16); nv += __shfl_xor(nv, 32);
    dv += __shfl_xor(dv, 16); dv += __shfl_xor(dv, 32);
    const float t = dv / (nv + 1e-12f);

    const int b = bh >> 4, h = bh & 15;
    const int tok = b * SS + q0 + ln15;
    #pragma unroll
    for (int c = 0; c < 4; c++) {
        short4v pk = { f2bf(o[c][0] - v4[c][0] * t), f2bf(o[c][1] - v4[c][1] * t),
                       f2bf(o[c][2] - v4[c][2] * t), f2bf(o[c][3] - v4[c][3] * t) };
        *(short4v*)(yb + (size_t)tok * 1024 + h * 64 + c * 16 + 4 * g) = pk;
    }
}

// ---------------------------------------------------------------------------
// Launch
// ---------------------------------------------------------------------------
extern "C" void kernel_launch(void* const* d_in, const int* in_sizes, int n_in,
                              void* d_out, int out_size, void* d_ws, size_t ws_size,
                              hipStream_t stream)
{
    const float* x  = (const float*)d_in[0];
    const float* Wq = (const float*)d_in[1];
    const float* bq = (const float*)d_in[2];
    const float* Wk = (const float*)d_in[3];
    const float* bk = (const float*)d_in[4];
    const float* Wv = (const float*)d_in[5];
    const float* bv = (const float*)d_in[6];
    const float* Wo = (const float*)d_in[7];
    const float* bo = (const float*)d_in[8];
    float* out = (float*)d_out;

    // ws: xb 8M | Wt 6M | Wot 2M | bcat | Qh 8M | Kh 8M | Vt 8M | yb 8M  (~49 MB)
    char* w = (char*)d_ws;
    short* xb   = (short*)(w);
    short* Wt   = (short*)(w + (8ull << 20));    // [3072][1024] bf16 (Q|K|V, n-major)
    short* Wot  = (short*)(w + (14ull << 20));   // [1024][1024] bf16
    float* bcat = (float*)(w + (16ull << 20));   // [3072]
    short* Qh   = (short*)(w + (17ull << 20));
    short* Kh   = (short*)(w + (25ull << 20));
    short* Vt   = (short*)(w + (33ull << 20));
    short* yb   = (short*)(w + (41ull << 20));

    const float qscale = 0.125f * 1.44269504f;   // 1/sqrt(HD) * log2(e)
    dim3 blk(256);

    conv_x<<<2048, blk, 0, stream>>>(x, xb);
    conv_wT<<<dim3(16, 16), blk, 0, stream>>>(Wq, Wt, qscale);
    conv_wT<<<dim3(16, 16), blk, 0, stream>>>(Wk, Wt + (1 << 20), 1.f);
    conv_wT<<<dim3(16, 16), blk, 0, stream>>>(Wv, Wt + (2 << 20), 1.f);
    conv_wT<<<dim3(16, 16), blk, 0, stream>>>(Wo, Wot, 1.f);
    conv_bias<<<12, blk, 0, stream>>>(bq, bk, bv, bcat, qscale);

    // QK projections (N = 2048 region of Wt), V projection (last 1024 rows)
    gemm_mfma<0><<<dim3(32, 16), blk, 0, stream>>>(xb, Wt, bcat, Qh, Kh, nullptr);
    gemm_mfma<1><<<dim3(32, 8), blk, 0, stream>>>(xb, Wt + (2ull << 20), bcat + 2048,
                                                  Vt, nullptr, nullptr);

    attn_mfma_kernel<<<dim3(BB * HH * SS / 64), blk, 0, stream>>>(Qh, Kh, Vt, yb);

    gemm_mfma<2><<<dim3(32, 8), blk, 0, stream>>>(yb, Wot, bo, nullptr, nullptr, out);
}

// Round 4
// 174.786 us; speedup vs baseline: 49.3605x; 2.4603x over previous
//
#include <hip/hip_runtime.h>

#define BB 2
#define SS 2048
#define DD 1024
#define HH 16
#define HDD 64

typedef __attribute__((ext_vector_type(4))) float f32x4;
typedef __attribute__((ext_vector_type(8))) short short8;
typedef __attribute__((ext_vector_type(4))) short short4v;

__device__ __forceinline__ short f2bf(float f) {
    union { float f; unsigned u; } a; a.f = f;
    unsigned r = a.u + 0x7fffu + ((a.u >> 16) & 1u);
    return (short)(r >> 16);
}
__device__ __forceinline__ float bf2f(short s) {
    union { unsigned u; float f; } a; a.u = ((unsigned)(unsigned short)s) << 16;
    return a.f;
}

#define GLD16(gp, lp) __builtin_amdgcn_global_load_lds( \
    (const __attribute__((address_space(1))) void*)(gp), \
    (__attribute__((address_space(3))) void*)(lp), 16, 0, 0)

// ---------------------------------------------------------------------------
// Converts
// ---------------------------------------------------------------------------
__global__ __launch_bounds__(256) void conv_x(const float* __restrict__ src,
                                              short* __restrict__ dst)
{
    const int i = (blockIdx.x * 256 + threadIdx.x) * 8;
    f32x4 a = *(const f32x4*)(src + i);
    f32x4 b = *(const f32x4*)(src + i + 4);
    short8 o;
    #pragma unroll
    for (int j = 0; j < 4; j++) { o[j] = f2bf(a[j]); o[j + 4] = f2bf(b[j]); }
    *(short8*)(dst + i) = o;
}

// src fp32 [1024 k][1024 n] -> dst bf16 [1024 n][1024 k], scaled
__global__ __launch_bounds__(256) void conv_wT(const float* __restrict__ src,
                                               short* __restrict__ dst, float scale)
{
    __shared__ float t[64][65];
    const int tid = threadIdx.x;
    const int c = tid & 63, rg = tid >> 6;
    const int bi = blockIdx.x * 64, bj = blockIdx.y * 64;
    #pragma unroll
    for (int i = 0; i < 16; i++)
        t[rg * 16 + i][c] = src[(size_t)(bi + rg * 16 + i) * 1024 + bj + c];
    __syncthreads();
    #pragma unroll
    for (int i = 0; i < 16; i++)
        dst[(size_t)(bj + rg * 16 + i) * 1024 + bi + c] = f2bf(scale * t[c][rg * 16 + i]);
}

__global__ __launch_bounds__(256) void conv_bias(const float* __restrict__ bq,
                                                 const float* __restrict__ bk,
                                                 const float* __restrict__ bv,
                                                 float* __restrict__ bcat, float qscale)
{
    const int i = blockIdx.x * 256 + threadIdx.x;   // grid 12 -> 3072
    float v = (i < 1024) ? bq[i] * qscale : (i < 2048 ? bk[i - 1024] : bv[i - 2048]);
    bcat[i] = v;
}

// ---------------------------------------------------------------------------
// bf16 MFMA GEMM (unchanged from round 3): 128x128 tile, BK=64, 4 waves.
// ---------------------------------------------------------------------------
template<int MODE>
__global__ __launch_bounds__(256) void gemm_mfma(
    const short* __restrict__ A, const short* __restrict__ Bt,
    const float* __restrict__ bias,
    short* __restrict__ o0, short* __restrict__ o1, float* __restrict__ of)
{
    __shared__ short lds[16384];          // As 16KB | Bs 16KB
    const int tid = threadIdx.x;
    const int lane = tid & 63;
    const int ln15 = lane & 15;
    const int g = lane >> 4;
    const int wid = tid >> 6;
    const int wm = wid >> 1, wn = wid & 1;
    const int bm = blockIdx.x * 128;
    const int bn = blockIdx.y * 128;

    f32x4 acc[4][4];
    #pragma unroll
    for (int i = 0; i < 4; i++)
        #pragma unroll
        for (int j = 0; j < 4; j++) acc[i][j] = (f32x4){0.f, 0.f, 0.f, 0.f};

    const int r_s = tid >> 3;
    const int cc_s = tid & 7;

    for (int k0 = 0; k0 < 1024; k0 += 64) {
        __syncthreads();
        #pragma unroll
        for (int i = 0; i < 4; i++) {
            const int r = r_s + i * 32;
            short8 v = *(const short8*)(A + (size_t)(bm + r) * 1024 + k0 + cc_s * 8);
            *(short8*)((char*)lds + r * 128 + ((cc_s ^ (r & 7)) << 4)) = v;
        }
        #pragma unroll
        for (int i = 0; i < 4; i++) {
            const int r = r_s + i * 32;
            short8 v = *(const short8*)(Bt + (size_t)(bn + r) * 1024 + k0 + cc_s * 8);
            *(short8*)((char*)lds + 16384 + r * 128 + ((cc_s ^ (r & 7)) << 4)) = v;
        }
        __syncthreads();

        #pragma unroll
        for (int kk = 0; kk < 2; kk++) {
            short8 af[4], bf[4];
            #pragma unroll
            for (int f = 0; f < 4; f++) {
                const int ra = wm * 64 + f * 16 + ln15;
                af[f] = *(const short8*)((char*)lds + ra * 128 +
                                         ((((kk << 2) | g) ^ (ra & 7)) << 4));
                const int rb = wn * 64 + f * 16 + ln15;
                bf[f] = *(const short8*)((char*)lds + 16384 + rb * 128 +
                                         ((((kk << 2) | g) ^ (rb & 7)) << 4));
            }
            #pragma unroll
            for (int fm = 0; fm < 4; fm++)
                #pragma unroll
                for (int fn = 0; fn < 4; fn++) {
                    if constexpr (MODE == 1)
                        acc[fm][fn] = __builtin_amdgcn_mfma_f32_16x16x32_bf16(
                            af[fm], bf[fn], acc[fm][fn], 0, 0, 0);
                    else
                        acc[fm][fn] = __builtin_amdgcn_mfma_f32_16x16x32_bf16(
                            bf[fn], af[fm], acc[fm][fn], 0, 0, 0);
                }
        }
    }

    const int n_base = bn + wn * 64;

    if constexpr (MODE == 0) {
        short* dst = (n_base < 1024) ? o0 : o1;
        #pragma unroll
        for (int fn = 0; fn < 4; fn++) {
            const int n0 = n_base + fn * 16 + 4 * g;
            const f32x4 b4 = *(const f32x4*)(bias + n0);
            const int nl = n0 & 1023;
            const int h = nl >> 6, d = nl & 63;
            #pragma unroll
            for (int fm = 0; fm < 4; fm++) {
                const int t = bm + wm * 64 + fm * 16 + ln15;
                const int b = t >> 11, s = t & 2047;
                short4v pk = { f2bf(acc[fm][fn][0] + b4[0]), f2bf(acc[fm][fn][1] + b4[1]),
                               f2bf(acc[fm][fn][2] + b4[2]), f2bf(acc[fm][fn][3] + b4[3]) };
                *(short4v*)(dst + ((size_t)(b * HH + h) * SS + s) * HDD + d) = pk;
            }
        }
    } else if constexpr (MODE == 1) {
        #pragma unroll
        for (int fn = 0; fn < 4; fn++) {
            const int nl = n_base + fn * 16 + ln15;
            const float bb = bias[nl];
            const int h = nl >> 6, d = nl & 63;
            #pragma unroll
            for (int fm = 0; fm < 4; fm++) {
                const int t0 = bm + wm * 64 + fm * 16 + 4 * g;
                const int b = t0 >> 11, s0 = t0 & 2047;
                short4v pk = { f2bf(acc[fm][fn][0] + bb), f2bf(acc[fm][fn][1] + bb),
                               f2bf(acc[fm][fn][2] + bb), f2bf(acc[fm][fn][3] + bb) };
                *(short4v*)(o0 + ((size_t)(b * HH + h) * HDD + d) * SS + s0) = pk;
            }
        }
    } else {
        #pragma unroll
        for (int fn = 0; fn < 4; fn++) {
            const int n0 = n_base + fn * 16 + 4 * g;
            const f32x4 b4 = *(const f32x4*)(bias + n0);
            #pragma unroll
            for (int fm = 0; fm < 4; fm++) {
                const int t = bm + wm * 64 + fm * 16 + ln15;
                f32x4 o = acc[fm][fn] + b4;
                *(f32x4*)(of + (size_t)t * 1024 + n0) = o;
            }
        }
    }
}

// ---------------------------------------------------------------------------
// MFMA flash attention, block-cooperative:
//  - 1 block = 4 waves = 64 q rows of one (b,h); KVBLK=64 keys/tile.
//  - K,V staged to LDS via global_load_lds, double-buffered, XOR-swizzled
//    (inverse-swizzle on global source, swizzle on ds_read).
//  - lane-local l, defer-max (THR=8 in log2 domain): no cross-lane ops on
//    the common path.
//  - raw s_barrier + manual waitcnt (one barrier per tile).
// ---------------------------------------------------------------------------
__global__ __launch_bounds__(256) void attn_mfma_kernel(
    const short* __restrict__ Qh, const short* __restrict__ Kh,
    const short* __restrict__ Vt, short* __restrict__ yb)
{
    __shared__ short lds[16384];               // [2 buf][K 4096 | V 4096] shorts

    const int lane = threadIdx.x & 63;
    const int wid  = threadIdx.x >> 6;
    const int ln15 = lane & 15;
    const int g    = lane >> 4;

    // XCD swizzle: 32 consecutive blocks share one (b,h) -> same XCD L2
    const int bid  = ((int)blockIdx.x & 7) * 128 + ((int)blockIdx.x >> 3);
    const int bh   = bid >> 5;                 // b*16 + h
    const int q0   = (bid & 31) * 64 + wid * 16;

    const short* qbase = Qh + (size_t)bh * SS * HDD;
    const short* kbase = Kh + (size_t)bh * SS * HDD;
    const short* vtb   = Vt + (size_t)bh * HDD * SS;

    const short8 qf0 = *(const short8*)(qbase + (size_t)(q0 + ln15) * HDD + g * 8);
    const short8 qf1 = *(const short8*)(qbase + (size_t)(q0 + ln15) * HDD + 32 + g * 8);

    const int sr = lane >> 3;                  // staging row-in-8 (== rr&7)
    const int cs = lane & 7;                   // staging chunk
    const int sc8 = (cs ^ sr) << 3;            // inverse-swizzled chunk, shorts

    // stage 64-key tile (keys s0..s0+63) into buffer b
    auto stage = [&](int b, int s0) {
        #pragma unroll
        for (int j = 0; j < 2; j++) {
            const int rr = wid * 16 + j * 8 + sr;
            GLD16(kbase + (size_t)(s0 + rr) * HDD + sc8,
                  &lds[b * 8192 + (wid * 16 + j * 8) * 64]);
            GLD16(vtb + (size_t)rr * SS + s0 + sc8,
                  &lds[b * 8192 + 4096 + (wid * 16 + j * 8) * 64]);
        }
    };

    f32x4 o[4];
    #pragma unroll
    for (int c = 0; c < 4; c++) o[c] = (f32x4){0.f, 0.f, 0.f, 0.f};
    float m = -1e30f, l = 0.f;

    stage(0, 0);
    asm volatile("s_waitcnt vmcnt(0)" ::: "memory");
    __builtin_amdgcn_s_barrier();

    for (int t = 0; t < SS / 64; ++t) {
        const int cur = t & 1;
        if (t < SS / 64 - 1) stage(cur ^ 1, (t + 1) * 64);

        // ---- QK^T: scores s[kg][r] = score(key kg*16+4g+r, q ln15)
        const char* kb = (const char*)lds + cur * 16384;
        short8 kf[4][2];
        #pragma unroll
        for (int kg = 0; kg < 4; kg++) {
            const int rk = kg * 16 + ln15;
            #pragma unroll
            for (int c = 0; c < 2; c++)
                kf[kg][c] = *(const short8*)(kb + rk * 128 +
                                             (((c * 4 + g) ^ (rk & 7)) << 4));
        }
        const f32x4 z = {0.f, 0.f, 0.f, 0.f};
        f32x4 s[4];
        __builtin_amdgcn_s_setprio(1);
        #pragma unroll
        for (int kg = 0; kg < 4; kg++) {
            s[kg] = __builtin_amdgcn_mfma_f32_16x16x32_bf16(kf[kg][0], qf0, z, 0, 0, 0);
            s[kg] = __builtin_amdgcn_mfma_f32_16x16x32_bf16(kf[kg][1], qf1, s[kg], 0, 0, 0);
        }
        __builtin_amdgcn_s_setprio(0);

        // ---- softmax (common path: no cross-lane ops)
        float t0 = fmaxf(fmaxf(s[0][0], s[0][1]), fmaxf(s[0][2], s[0][3]));
        float t1 = fmaxf(fmaxf(s[1][0], s[1][1]), fmaxf(s[1][2], s[1][3]));
        float t2 = fmaxf(fmaxf(s[2][0], s[2][1]), fmaxf(s[2][2], s[2][3]));
        float t3 = fmaxf(fmaxf(s[3][0], s[3][1]), fmaxf(s[3][2], s[3][3]));
        float pm = fmaxf(fmaxf(t0, t1), fmaxf(t2, t3));
        if (__any(pm > m + 8.f)) {              // rare rescale path
            pm = fmaxf(pm, __shfl_xor(pm, 16));
            pm = fmaxf(pm, __shfl_xor(pm, 32));
            const float mn = fmaxf(m, pm);
            const float corr = exp2f(m - mn);
            l *= corr;
            #pragma unroll
            for (int c = 0; c < 4; c++) o[c] *= corr;
            m = mn;
        }
        float p[4][4];
        float ps = 0.f;
        #pragma unroll
        for (int kg = 0; kg < 4; kg++)
            #pragma unroll
            for (int r = 0; r < 4; r++) {
                p[kg][r] = exp2f(s[kg][r] - m);
                ps += p[kg][r];
            }
        l += ps;

        short8 pf0, pf1;
        #pragma unroll
        for (int e = 0; e < 4; e++) {
            pf0[e] = f2bf(p[0][e]); pf0[e + 4] = f2bf(p[1][e]);
            pf1[e] = f2bf(p[2][e]); pf1[e + 4] = f2bf(p[3][e]);
        }

        // ---- PV: o[c] rows d = c*16+4g+r, col q = ln15
        const char* vb = (const char*)lds + cur * 16384 + 8192;
        const int g2 = g >> 1, gb = (g & 1) * 8;
        __builtin_amdgcn_s_setprio(1);
        #pragma unroll
        for (int c = 0; c < 4; c++) {
            const int rv = c * 16 + ln15;
            const int sw = rv & 7;
            const char* row = vb + rv * 128 + gb;
            short4v a0 = *(const short4v*)(row + ((g2 ^ sw) << 4));
            short4v a1 = *(const short4v*)(row + (((g2 + 2) ^ sw) << 4));
            short4v b0 = *(const short4v*)(row + (((g2 + 4) ^ sw) << 4));
            short4v b1 = *(const short4v*)(row + (((g2 + 6) ^ sw) << 4));
            short8 vf0, vf1;
            #pragma unroll
            for (int e = 0; e < 4; e++) {
                vf0[e] = a0[e]; vf0[e + 4] = a1[e];
                vf1[e] = b0[e]; vf1[e + 4] = b1[e];
            }
            o[c] = __builtin_amdgcn_mfma_f32_16x16x32_bf16(vf0, pf0, o[c], 0, 0, 0);
            o[c] = __builtin_amdgcn_mfma_f32_16x16x32_bf16(vf1, pf1, o[c], 0, 0, 0);
        }
        __builtin_amdgcn_s_setprio(0);

        asm volatile("s_waitcnt vmcnt(0) lgkmcnt(0)" ::: "memory");
        __builtin_amdgcn_s_barrier();
    }

    // total l across the 4 lane-groups
    l += __shfl_xor(l, 16);
    l += __shfl_xor(l, 32);
    const float inv = 1.f / l;
    #pragma unroll
    for (int c = 0; c < 4; c++) o[c] *= inv;

    // exclusive postprocess: y -= (y . v_norm) v_norm   (v from bf16 Vt)
    float v4[4][4];
    float nv = 0.f, dv = 0.f;
    #pragma unroll
    for (int c = 0; c < 4; c++)
        #pragma unroll
        for (int r = 0; r < 4; r++) {
            const float vd = bf2f(vtb[(size_t)(c * 16 + 4 * g + r) * SS + q0 + ln15]);
            v4[c][r] = vd;
            nv += vd * vd;
            dv += o[c][r] * vd;
        }
    nv += __shfl_xor(nv, 16); nv += __shfl_xor(nv, 32);
    dv += __shfl_xor(dv, 16); dv += __shfl_xor(dv, 32);
    const float tpp = dv / (nv + 1e-12f);

    const int b = bh >> 4, h = bh & 15;
    const int tok = b * SS + q0 + ln15;
    #pragma unroll
    for (int c = 0; c < 4; c++) {
        short4v pk = { f2bf(o[c][0] - v4[c][0] * tpp), f2bf(o[c][1] - v4[c][1] * tpp),
                       f2bf(o[c][2] - v4[c][2] * tpp), f2bf(o[c][3] - v4[c][3] * tpp) };
        *(short4v*)(yb + (size_t)tok * 1024 + h * 64 + c * 16 + 4 * g) = pk;
    }
}

// ---------------------------------------------------------------------------
// Launch
// ---------------------------------------------------------------------------
extern "C" void kernel_launch(void* const* d_in, const int* in_sizes, int n_in,
                              void* d_out, int out_size, void* d_ws, size_t ws_size,
                              hipStream_t stream)
{
    const float* x  = (const float*)d_in[0];
    const float* Wq = (const float*)d_in[1];
    const float* bq = (const float*)d_in[2];
    const float* Wk = (const float*)d_in[3];
    const float* bk = (const float*)d_in[4];
    const float* Wv = (const float*)d_in[5];
    const float* bv = (const float*)d_in[6];
    const float* Wo = (const float*)d_in[7];
    const float* bo = (const float*)d_in[8];
    float* out = (float*)d_out;

    // ws: xb 8M | Wt 6M | Wot 2M | bcat | Qh 8M | Kh 8M | Vt 8M | yb 8M  (~49 MB)
    char* w = (char*)d_ws;
    short* xb   = (short*)(w);
    short* Wt   = (short*)(w + (8ull << 20));    // [3072][1024] bf16 (Q|K|V, n-major)
    short* Wot  = (short*)(w + (14ull << 20));   // [1024][1024] bf16
    float* bcat = (float*)(w + (16ull << 20));   // [3072]
    short* Qh   = (short*)(w + (17ull << 20));
    short* Kh   = (short*)(w + (25ull << 20));
    short* Vt   = (short*)(w + (33ull << 20));
    short* yb   = (short*)(w + (41ull << 20));

    const float qscale = 0.125f * 1.44269504f;   // 1/sqrt(HD) * log2(e)
    dim3 blk(256);

    conv_x<<<2048, blk, 0, stream>>>(x, xb);
    conv_wT<<<dim3(16, 16), blk, 0, stream>>>(Wq, Wt, qscale);
    conv_wT<<<dim3(16, 16), blk, 0, stream>>>(Wk, Wt + (1 << 20), 1.f);
    conv_wT<<<dim3(16, 16), blk, 0, stream>>>(Wv, Wt + (2 << 20), 1.f);
    conv_wT<<<dim3(16, 16), blk, 0, stream>>>(Wo, Wot, 1.f);
    conv_bias<<<12, blk, 0, stream>>>(bq, bk, bv, bcat, qscale);

    gemm_mfma<0><<<dim3(32, 16), blk, 0, stream>>>(xb, Wt, bcat, Qh, Kh, nullptr);
    gemm_mfma<1><<<dim3(32, 8), blk, 0, stream>>>(xb, Wt + (2ull << 20), bcat + 2048,
                                                  Vt, nullptr, nullptr);

    attn_mfma_kernel<<<dim3(BB * HH * SS / 64), blk, 0, stream>>>(Qh, Kh, Vt, yb);

    gemm_mfma<2><<<dim3(32, 8), blk, 0, stream>>>(yb, Wot, bo, nullptr, nullptr, out);
}

// Round 5
// 151.456 us; speedup vs baseline: 56.9641x; 1.1540x over previous
//
#include <hip/hip_runtime.h>

#define BB 2
#define SS 2048
#define DD 1024
#define HH 16
#define HDD 64

typedef __attribute__((ext_vector_type(4))) float f32x4;
typedef __attribute__((ext_vector_type(8))) short short8;
typedef __attribute__((ext_vector_type(4))) short short4v;

__device__ __forceinline__ short f2bf(float f) {
    union { float f; unsigned u; } a; a.f = f;
    unsigned r = a.u + 0x7fffu + ((a.u >> 16) & 1u);
    return (short)(r >> 16);
}
__device__ __forceinline__ float bf2f(short s) {
    union { unsigned u; float f; } a; a.u = ((unsigned)(unsigned short)s) << 16;
    return a.f;
}
__device__ __forceinline__ float fast_exp2(float x) {
    float r;
    asm("v_exp_f32 %0, %1\n\ts_nop 0" : "=v"(r) : "v"(x));
    return r;
}
__device__ __forceinline__ unsigned cvt_pk_bf16(float lo, float hi) {
    unsigned r;
    asm("v_cvt_pk_bf16_f32 %0, %1, %2" : "=v"(r) : "v"(lo), "v"(hi));
    return r;
}

#define GLD16(gp, lp) __builtin_amdgcn_global_load_lds( \
    (const __attribute__((address_space(1))) void*)(gp), \
    (__attribute__((address_space(3))) void*)(lp), 16, 0, 0)

// ---------------------------------------------------------------------------
// Converts
// ---------------------------------------------------------------------------
__global__ __launch_bounds__(256) void conv_x(const float* __restrict__ src,
                                              short* __restrict__ dst)
{
    const int i = (blockIdx.x * 256 + threadIdx.x) * 8;
    f32x4 a = *(const f32x4*)(src + i);
    f32x4 b = *(const f32x4*)(src + i + 4);
    short8 o;
    #pragma unroll
    for (int j = 0; j < 4; j++) { o[j] = f2bf(a[j]); o[j + 4] = f2bf(b[j]); }
    *(short8*)(dst + i) = o;
}

// src fp32 [1024 k][1024 n] -> dst bf16 [1024 n][1024 k], scaled
__global__ __launch_bounds__(256) void conv_wT(const float* __restrict__ src,
                                               short* __restrict__ dst, float scale)
{
    __shared__ float t[64][65];
    const int tid = threadIdx.x;
    const int c = tid & 63, rg = tid >> 6;
    const int bi = blockIdx.x * 64, bj = blockIdx.y * 64;
    #pragma unroll
    for (int i = 0; i < 16; i++)
        t[rg * 16 + i][c] = src[(size_t)(bi + rg * 16 + i) * 1024 + bj + c];
    __syncthreads();
    #pragma unroll
    for (int i = 0; i < 16; i++)
        dst[(size_t)(bj + rg * 16 + i) * 1024 + bi + c] = f2bf(scale * t[c][rg * 16 + i]);
}

__global__ __launch_bounds__(256) void conv_bias(const float* __restrict__ bq,
                                                 const float* __restrict__ bk,
                                                 const float* __restrict__ bv,
                                                 float* __restrict__ bcat, float qscale)
{
    const int i = blockIdx.x * 256 + threadIdx.x;   // grid 12 -> 3072
    float v = (i < 1024) ? bq[i] * qscale : (i < 2048 ? bk[i - 1024] : bv[i - 2048]);
    bcat[i] = v;
}

// ---------------------------------------------------------------------------
// bf16 MFMA GEMM: 128x128 tile, BK=64, 4 waves.
// MODE 1 (V) stores Vt with PERMUTED key order within each 64-key block:
//   pos(s) = g*16 + (kg&1)*4 + (kg>>1)*8 + r  where s = kg*16 + 4g + r,
// so the attention PV fragment is one contiguous 16B read per half.
// ---------------------------------------------------------------------------
template<int MODE>
__global__ __launch_bounds__(256) void gemm_mfma(
    const short* __restrict__ A, const short* __restrict__ Bt,
    const float* __restrict__ bias,
    short* __restrict__ o0, short* __restrict__ o1, float* __restrict__ of)
{
    __shared__ short lds[16384];          // As 16KB | Bs 16KB
    const int tid = threadIdx.x;
    const int lane = tid & 63;
    const int ln15 = lane & 15;
    const int g = lane >> 4;
    const int wid = tid >> 6;
    const int wm = wid >> 1, wn = wid & 1;
    const int bm = blockIdx.x * 128;
    const int bn = blockIdx.y * 128;

    f32x4 acc[4][4];
    #pragma unroll
    for (int i = 0; i < 4; i++)
        #pragma unroll
        for (int j = 0; j < 4; j++) acc[i][j] = (f32x4){0.f, 0.f, 0.f, 0.f};

    const int r_s = tid >> 3;
    const int cc_s = tid & 7;

    for (int k0 = 0; k0 < 1024; k0 += 64) {
        __syncthreads();
        #pragma unroll
        for (int i = 0; i < 4; i++) {
            const int r = r_s + i * 32;
            short8 v = *(const short8*)(A + (size_t)(bm + r) * 1024 + k0 + cc_s * 8);
            *(short8*)((char*)lds + r * 128 + ((cc_s ^ (r & 7)) << 4)) = v;
        }
        #pragma unroll
        for (int i = 0; i < 4; i++) {
            const int r = r_s + i * 32;
            short8 v = *(const short8*)(Bt + (size_t)(bn + r) * 1024 + k0 + cc_s * 8);
            *(short8*)((char*)lds + 16384 + r * 128 + ((cc_s ^ (r & 7)) << 4)) = v;
        }
        __syncthreads();

        #pragma unroll
        for (int kk = 0; kk < 2; kk++) {
            short8 af[4], bf[4];
            #pragma unroll
            for (int f = 0; f < 4; f++) {
                const int ra = wm * 64 + f * 16 + ln15;
                af[f] = *(const short8*)((char*)lds + ra * 128 +
                                         ((((kk << 2) | g) ^ (ra & 7)) << 4));
                const int rb = wn * 64 + f * 16 + ln15;
                bf[f] = *(const short8*)((char*)lds + 16384 + rb * 128 +
                                         ((((kk << 2) | g) ^ (rb & 7)) << 4));
            }
            #pragma unroll
            for (int fm = 0; fm < 4; fm++)
                #pragma unroll
                for (int fn = 0; fn < 4; fn++) {
                    if constexpr (MODE == 1)
                        acc[fm][fn] = __builtin_amdgcn_mfma_f32_16x16x32_bf16(
                            af[fm], bf[fn], acc[fm][fn], 0, 0, 0);
                    else
                        acc[fm][fn] = __builtin_amdgcn_mfma_f32_16x16x32_bf16(
                            bf[fn], af[fm], acc[fm][fn], 0, 0, 0);
                }
        }
    }

    const int n_base = bn + wn * 64;

    if constexpr (MODE == 0) {
        short* dst = (n_base < 1024) ? o0 : o1;
        #pragma unroll
        for (int fn = 0; fn < 4; fn++) {
            const int n0 = n_base + fn * 16 + 4 * g;
            const f32x4 b4 = *(const f32x4*)(bias + n0);
            const int nl = n0 & 1023;
            const int h = nl >> 6, d = nl & 63;
            #pragma unroll
            for (int fm = 0; fm < 4; fm++) {
                const int t = bm + wm * 64 + fm * 16 + ln15;
                const int b = t >> 11, s = t & 2047;
                short4v pk = { f2bf(acc[fm][fn][0] + b4[0]), f2bf(acc[fm][fn][1] + b4[1]),
                               f2bf(acc[fm][fn][2] + b4[2]), f2bf(acc[fm][fn][3] + b4[3]) };
                *(short4v*)(dst + ((size_t)(b * HH + h) * SS + s) * HDD + d) = pk;
            }
        }
    } else if constexpr (MODE == 1) {
        #pragma unroll
        for (int fn = 0; fn < 4; fn++) {
            const int nl = n_base + fn * 16 + ln15;
            const float bb = bias[nl];
            const int h = nl >> 6, d = nl & 63;
            #pragma unroll
            for (int fm = 0; fm < 4; fm++) {
                const int t0 = bm + wm * 64 + fm * 16 + 4 * g;
                const int b = t0 >> 11;
                const int sb = (t0 & 2047) & ~63;                 // 64-block base
                const int pos = g * 16 + (fm & 1) * 4 + ((fm >> 1) & 1) * 8;
                short4v pk = { f2bf(acc[fm][fn][0] + bb), f2bf(acc[fm][fn][1] + bb),
                               f2bf(acc[fm][fn][2] + bb), f2bf(acc[fm][fn][3] + bb) };
                *(short4v*)(o0 + ((size_t)(b * HH + h) * HDD + d) * SS + sb + pos) = pk;
            }
        }
    } else {
        #pragma unroll
        for (int fn = 0; fn < 4; fn++) {
            const int n0 = n_base + fn * 16 + 4 * g;
            const f32x4 b4 = *(const f32x4*)(bias + n0);
            #pragma unroll
            for (int fm = 0; fm < 4; fm++) {
                const int t = bm + wm * 64 + fm * 16 + ln15;
                f32x4 o = acc[fm][fn] + b4;
                *(f32x4*)(of + (size_t)t * 1024 + n0) = o;
            }
        }
    }
}

// ---------------------------------------------------------------------------
// MFMA flash attention, block-cooperative, VALU-slimmed:
//  - K,V staged to LDS (global_load_lds, dbuf, XOR-swizzled).
//  - asm v_exp_f32 (log2 domain), asm v_cvt_pk_bf16_f32 for P packing.
//  - PV fragments: single b128 per half (permuted-key Vt layout).
//  - defer-max, lane-local l, one barrier per tile.
// ---------------------------------------------------------------------------
__global__ __launch_bounds__(256) void attn_mfma_kernel(
    const short* __restrict__ Qh, const short* __restrict__ Kh,
    const short* __restrict__ Vt, short* __restrict__ yb)
{
    __shared__ short lds[16384];               // [2 buf][K 4096 | V 4096] shorts

    const int lane = threadIdx.x & 63;
    const int wid  = threadIdx.x >> 6;
    const int ln15 = lane & 15;
    const int g    = lane >> 4;

    const int bid  = ((int)blockIdx.x & 7) * 128 + ((int)blockIdx.x >> 3);
    const int bh   = bid >> 5;                 // b*16 + h
    const int q0   = (bid & 31) * 64 + wid * 16;

    const short* qbase = Qh + (size_t)bh * SS * HDD;
    const short* kbase = Kh + (size_t)bh * SS * HDD;
    const short* vtb   = Vt + (size_t)bh * HDD * SS;

    const short8 qf0 = *(const short8*)(qbase + (size_t)(q0 + ln15) * HDD + g * 8);
    const short8 qf1 = *(const short8*)(qbase + (size_t)(q0 + ln15) * HDD + 32 + g * 8);

    const int sr = lane >> 3;                  // staging row-in-8 (== rr&7)
    const int cs = lane & 7;                   // staging chunk
    const int sc8 = (cs ^ sr) << 3;            // inverse-swizzled chunk, shorts

    auto stage = [&](int b, int s0) {
        #pragma unroll
        for (int j = 0; j < 2; j++) {
            const int rr = wid * 16 + j * 8 + sr;
            GLD16(kbase + (size_t)(s0 + rr) * HDD + sc8,
                  &lds[b * 8192 + (wid * 16 + j * 8) * 64]);
            GLD16(vtb + (size_t)rr * SS + s0 + sc8,
                  &lds[b * 8192 + 4096 + (wid * 16 + j * 8) * 64]);
        }
    };

    f32x4 o[4];
    #pragma unroll
    for (int c = 0; c < 4; c++) o[c] = (f32x4){0.f, 0.f, 0.f, 0.f};
    float m = -1e30f, l = 0.f;

    stage(0, 0);
    asm volatile("s_waitcnt vmcnt(0)" ::: "memory");
    __builtin_amdgcn_s_barrier();

    for (int t = 0; t < SS / 64; ++t) {
        const int cur = t & 1;
        if (t < SS / 64 - 1) stage(cur ^ 1, (t + 1) * 64);

        // ---- QK^T: s[kg][r] = score(key kg*16+4g+r, q ln15)
        const char* kb = (const char*)lds + cur * 16384;
        short8 kf[4][2];
        #pragma unroll
        for (int kg = 0; kg < 4; kg++) {
            const int rk = kg * 16 + ln15;
            #pragma unroll
            for (int c = 0; c < 2; c++)
                kf[kg][c] = *(const short8*)(kb + rk * 128 +
                                             (((c * 4 + g) ^ (rk & 7)) << 4));
        }
        const f32x4 z = {0.f, 0.f, 0.f, 0.f};
        f32x4 s[4];
        __builtin_amdgcn_s_setprio(1);
        #pragma unroll
        for (int kg = 0; kg < 4; kg++) {
            s[kg] = __builtin_amdgcn_mfma_f32_16x16x32_bf16(kf[kg][0], qf0, z, 0, 0, 0);
            s[kg] = __builtin_amdgcn_mfma_f32_16x16x32_bf16(kf[kg][1], qf1, s[kg], 0, 0, 0);
        }
        __builtin_amdgcn_s_setprio(0);

        // ---- softmax (no cross-lane ops on common path)
        const float pm = fmaxf(
            fmaxf(fmaxf(fmaxf(s[0][0], s[0][1]), fmaxf(s[0][2], s[0][3])),
                  fmaxf(fmaxf(s[1][0], s[1][1]), fmaxf(s[1][2], s[1][3]))),
            fmaxf(fmaxf(fmaxf(s[2][0], s[2][1]), fmaxf(s[2][2], s[2][3])),
                  fmaxf(fmaxf(s[3][0], s[3][1]), fmaxf(s[3][2], s[3][3]))));
        if (__any(pm > m + 8.f)) {
            float pmw = fmaxf(pm, __shfl_xor(pm, 16));
            pmw = fmaxf(pmw, __shfl_xor(pmw, 32));
            const float mn = fmaxf(m, pmw);
            const float corr = fast_exp2(m - mn);
            l *= corr;
            #pragma unroll
            for (int c = 0; c < 4; c++) o[c] *= corr;
            m = mn;
        }
        float p[4][4];
        #pragma unroll
        for (int kg = 0; kg < 4; kg++)
            #pragma unroll
            for (int r = 0; r < 4; r++)
                p[kg][r] = fast_exp2(s[kg][r] - m);
        const float ps =
            ((p[0][0] + p[0][1]) + (p[0][2] + p[0][3])) +
            ((p[1][0] + p[1][1]) + (p[1][2] + p[1][3])) +
            ((p[2][0] + p[2][1]) + (p[2][2] + p[2][3])) +
            ((p[3][0] + p[3][1]) + (p[3][2] + p[3][3]));
        l += ps;

        union { unsigned u[4]; short8 v; } P0, P1;
        P0.u[0] = cvt_pk_bf16(p[0][0], p[0][1]);
        P0.u[1] = cvt_pk_bf16(p[0][2], p[0][3]);
        P0.u[2] = cvt_pk_bf16(p[1][0], p[1][1]);
        P0.u[3] = cvt_pk_bf16(p[1][2], p[1][3]);
        P1.u[0] = cvt_pk_bf16(p[2][0], p[2][1]);
        P1.u[1] = cvt_pk_bf16(p[2][2], p[2][3]);
        P1.u[2] = cvt_pk_bf16(p[3][0], p[3][1]);
        P1.u[3] = cvt_pk_bf16(p[3][2], p[3][3]);

        // ---- PV: permuted-key layout -> one b128 per half-fragment
        const char* vb = kb + 8192;
        __builtin_amdgcn_s_setprio(1);
        #pragma unroll
        for (int c = 0; c < 4; c++) {
            const int rv = c * 16 + ln15;
            const int sw = ln15 & 7;
            short8 vf0 = *(const short8*)(vb + rv * 128 + (((2 * g) ^ sw) << 4));
            short8 vf1 = *(const short8*)(vb + rv * 128 + (((2 * g + 1) ^ sw) << 4));
            o[c] = __builtin_amdgcn_mfma_f32_16x16x32_bf16(vf0, P0.v, o[c], 0, 0, 0);
            o[c] = __builtin_amdgcn_mfma_f32_16x16x32_bf16(vf1, P1.v, o[c], 0, 0, 0);
        }
        __builtin_amdgcn_s_setprio(0);

        asm volatile("s_waitcnt vmcnt(0) lgkmcnt(0)" ::: "memory");
        __builtin_amdgcn_s_barrier();
    }

    l += __shfl_xor(l, 16);
    l += __shfl_xor(l, 32);
    const float inv = 1.f / l;
    #pragma unroll
    for (int c = 0; c < 4; c++) o[c] *= inv;

    // exclusive postprocess: y -= (y . v_norm) v_norm  (v from permuted Vt)
    const int qloc = wid * 16 + ln15;          // s & 63
    const int spos = (q0 & ~63) + (ln15 >> 2) * 16 + (wid & 1) * 4 +
                     ((wid >> 1) & 1) * 8 + (ln15 & 3);
    (void)qloc;
    float v4[4][4];
    float nv = 0.f, dv = 0.f;
    #pragma unroll
    for (int c = 0; c < 4; c++)
        #pragma unroll
        for (int r = 0; r < 4; r++) {
            const float vd = bf2f(vtb[(size_t)(c * 16 + 4 * g + r) * SS + spos]);
            v4[c][r] = vd;
            nv += vd * vd;
            dv += o[c][r] * vd;
        }
    nv += __shfl_xor(nv, 16); nv += __shfl_xor(nv, 32);
    dv += __shfl_xor(dv, 16); dv += __shfl_xor(dv, 32);
    const float tpp = dv / (nv + 1e-12f);

    const int b = bh >> 4, h = bh & 15;
    const int tok = b * SS + q0 + ln15;
    #pragma unroll
    for (int c = 0; c < 4; c++) {
        short4v pk = { f2bf(o[c][0] - v4[c][0] * tpp), f2bf(o[c][1] - v4[c][1] * tpp),
                       f2bf(o[c][2] - v4[c][2] * tpp), f2bf(o[c][3] - v4[c][3] * tpp) };
        *(short4v*)(yb + (size_t)tok * 1024 + h * 64 + c * 16 + 4 * g) = pk;
    }
}

// ---------------------------------------------------------------------------
// Launch
// ---------------------------------------------------------------------------
extern "C" void kernel_launch(void* const* d_in, const int* in_sizes, int n_in,
                              void* d_out, int out_size, void* d_ws, size_t ws_size,
                              hipStream_t stream)
{
    const float* x  = (const float*)d_in[0];
    const float* Wq = (const float*)d_in[1];
    const float* bq = (const float*)d_in[2];
    const float* Wk = (const float*)d_in[3];
    const float* bk = (const float*)d_in[4];
    const float* Wv = (const float*)d_in[5];
    const float* bv = (const float*)d_in[6];
    const float* Wo = (const float*)d_in[7];
    const float* bo = (const float*)d_in[8];
    float* out = (float*)d_out;

    // ws: xb 8M | Wt 6M | Wot 2M | bcat | Qh 8M | Kh 8M | Vt 8M | yb 8M  (~49 MB)
    char* w = (char*)d_ws;
    short* xb   = (short*)(w);
    short* Wt   = (short*)(w + (8ull << 20));    // [3072][1024] bf16 (Q|K|V, n-major)
    short* Wot  = (short*)(w + (14ull << 20));   // [1024][1024] bf16
    float* bcat = (float*)(w + (16ull << 20));   // [3072]
    short* Qh   = (short*)(w + (17ull << 20));
    short* Kh   = (short*)(w + (25ull << 20));
    short* Vt   = (short*)(w + (33ull << 20));
    short* yb   = (short*)(w + (41ull << 20));

    const float qscale = 0.125f * 1.44269504f;   // 1/sqrt(HD) * log2(e)
    dim3 blk(256);

    conv_x<<<2048, blk, 0, stream>>>(x, xb);
    conv_wT<<<dim3(16, 16), blk, 0, stream>>>(Wq, Wt, qscale);
    conv_wT<<<dim3(16, 16), blk, 0, stream>>>(Wk, Wt + (1 << 20), 1.f);
    conv_wT<<<dim3(16, 16), blk, 0, stream>>>(Wv, Wt + (2 << 20), 1.f);
    conv_wT<<<dim3(16, 16), blk, 0, stream>>>(Wo, Wot, 1.f);
    conv_bias<<<12, blk, 0, stream>>>(bq, bk, bv, bcat, qscale);

    gemm_mfma<0><<<dim3(32, 16), blk, 0, stream>>>(xb, Wt, bcat, Qh, Kh, nullptr);
    gemm_mfma<1><<<dim3(32, 8), blk, 0, stream>>>(xb, Wt + (2ull << 20), bcat + 2048,
                                                  Vt, nullptr, nullptr);

    attn_mfma_kernel<<<dim3(BB * HH * SS / 64), blk, 0, stream>>>(Qh, Kh, Vt, yb);

    gemm_mfma<2><<<dim3(32, 8), blk, 0, stream>>>(yb, Wot, bo, nullptr, nullptr, out);
}

// Round 6
// 112.799 us; speedup vs baseline: 76.4858x; 1.3427x over previous
//
#include <hip/hip_runtime.h>

#define BB 2
#define SS 2048
#define DD 1024
#define HH 16
#define HDD 64

typedef __attribute__((ext_vector_type(4))) float f32x4;
typedef __attribute__((ext_vector_type(8))) short short8;
typedef __attribute__((ext_vector_type(4))) short short4v;

__device__ __forceinline__ short f2bf(float f) {
    union { float f; unsigned u; } a; a.f = f;
    unsigned r = a.u + 0x7fffu + ((a.u >> 16) & 1u);
    return (short)(r >> 16);
}
__device__ __forceinline__ float bf2f(short s) {
    union { unsigned u; float f; } a; a.u = ((unsigned)(unsigned short)s) << 16;
    return a.f;
}
__device__ __forceinline__ float fast_exp2(float x) {
    float r;
    asm("v_exp_f32 %0, %1\n\ts_nop 0" : "=v"(r) : "v"(x));
    return r;
}
__device__ __forceinline__ unsigned cvt_pk_bf16(float lo, float hi) {
    unsigned r;
    asm("v_cvt_pk_bf16_f32 %0, %1, %2" : "=v"(r) : "v"(lo), "v"(hi));
    return r;
}
__device__ __forceinline__ float fmax3(float a, float b, float c) {
    float r;
    asm("v_max3_f32 %0, %1, %2, %3" : "=v"(r) : "v"(a), "v"(b), "v"(c));
    return r;
}

#define GLD16(gp, lp) __builtin_amdgcn_global_load_lds( \
    (const __attribute__((address_space(1))) void*)(gp), \
    (__attribute__((address_space(3))) void*)(lp), 16, 0, 0)

// ---------------------------------------------------------------------------
// Converts
// ---------------------------------------------------------------------------
__global__ __launch_bounds__(256) void conv_x(const float* __restrict__ src,
                                              short* __restrict__ dst)
{
    const int i = (blockIdx.x * 256 + threadIdx.x) * 8;
    f32x4 a = *(const f32x4*)(src + i);
    f32x4 b = *(const f32x4*)(src + i + 4);
    short8 o;
    #pragma unroll
    for (int j = 0; j < 4; j++) { o[j] = f2bf(a[j]); o[j + 4] = f2bf(b[j]); }
    *(short8*)(dst + i) = o;
}

// 4 weight transposes in one dispatch: z selects {Wq,Wk,Wv -> Wt, Wo -> Wot}
__global__ __launch_bounds__(256) void conv_w4(
    const float* __restrict__ Wq, const float* __restrict__ Wk,
    const float* __restrict__ Wv, const float* __restrict__ Wo,
    short* __restrict__ Wt, short* __restrict__ Wot, float qscale)
{
    __shared__ float t[64][65];
    const int z = blockIdx.z;
    const float* src = (z == 0) ? Wq : (z == 1) ? Wk : (z == 2) ? Wv : Wo;
    short* dst = (z < 3) ? (Wt + (size_t)z * 1048576) : Wot;
    const float scale = (z == 0) ? qscale : 1.f;

    const int tid = threadIdx.x;
    const int c = tid & 63, rg = tid >> 6;
    const int bi = blockIdx.x * 64, bj = blockIdx.y * 64;
    #pragma unroll
    for (int i = 0; i < 16; i++)
        t[rg * 16 + i][c] = src[(size_t)(bi + rg * 16 + i) * 1024 + bj + c];
    __syncthreads();
    #pragma unroll
    for (int i = 0; i < 16; i++)
        dst[(size_t)(bj + rg * 16 + i) * 1024 + bi + c] = f2bf(scale * t[c][rg * 16 + i]);
}

__global__ __launch_bounds__(256) void conv_bias(const float* __restrict__ bq,
                                                 const float* __restrict__ bk,
                                                 const float* __restrict__ bv,
                                                 float* __restrict__ bcat, float qscale)
{
    const int i = blockIdx.x * 256 + threadIdx.x;
    float v = (i < 1024) ? bq[i] * qscale : (i < 2048 ? bk[i - 1024] : bv[i - 2048]);
    bcat[i] = v;
}

// ---------------------------------------------------------------------------
// bf16 MFMA GEMM, global_load_lds + double-buffer, 128x128 tile, BK=64.
// KIND 0: fused QKV (Bt = Wt[3072][1024]); blockIdx.y<16 -> Q/K epilogue
//         (swapped operands), else V epilogue (normal operands, permuted Vt).
// KIND 1: out-proj, fp32 + bias.
// ---------------------------------------------------------------------------
template<int KIND>
__global__ __launch_bounds__(256, 2) void gemm_mfma(
    const short* __restrict__ A, const short* __restrict__ Bt,
    const float* __restrict__ bias,
    short* __restrict__ oQ, short* __restrict__ oK, short* __restrict__ oV,
    float* __restrict__ oF)
{
    __shared__ short lds[32768];          // 2 buf x (A 16KB | B 16KB)
    const int tid = threadIdx.x;
    const int lane = tid & 63;
    const int ln15 = lane & 15, g = lane >> 4;
    const int wid = tid >> 6;
    const int wm = wid >> 1, wn = wid & 1;
    const int bm = blockIdx.x * 128;
    const int bn = blockIdx.y * 128;
    const bool vpath = (KIND == 0) && (blockIdx.y >= 16);

    f32x4 acc[4][4];
    #pragma unroll
    for (int i = 0; i < 4; i++)
        #pragma unroll
        for (int j = 0; j < 4; j++) acc[i][j] = (f32x4){0.f, 0.f, 0.f, 0.f};

    const int sr = lane >> 3, cs = lane & 7;
    const int sc8 = (cs ^ sr) << 3;       // inverse-swizzled global chunk (shorts)
    const int rb = wid * 8;

    auto stage = [&](int buf, int k0) {
        #pragma unroll
        for (int j = 0; j < 4; j++) {
            const int r = rb + j * 32 + sr;
            GLD16(A + (size_t)(bm + r) * 1024 + k0 + sc8,
                  &lds[buf * 16384 + (rb + j * 32) * 64]);
            GLD16(Bt + (size_t)(bn + r) * 1024 + k0 + sc8,
                  &lds[buf * 16384 + 8192 + (rb + j * 32) * 64]);
        }
    };

    stage(0, 0);
    asm volatile("s_waitcnt vmcnt(0)" ::: "memory");
    __builtin_amdgcn_s_barrier();

    for (int t = 0; t < 16; ++t) {
        const int cur = t & 1;
        if (t < 15) stage(cur ^ 1, (t + 1) * 64);
        const char* base = (const char*)lds + cur * 32768;

        #pragma unroll
        for (int kk = 0; kk < 2; kk++) {
            short8 af[4], bf[4];
            #pragma unroll
            for (int f = 0; f < 4; f++) {
                const int ra = wm * 64 + f * 16 + ln15;
                af[f] = *(const short8*)(base + ra * 128 +
                                         ((((kk << 2) | g) ^ (ra & 7)) << 4));
                const int rbv = wn * 64 + f * 16 + ln15;
                bf[f] = *(const short8*)(base + 16384 + rbv * 128 +
                                         ((((kk << 2) | g) ^ (rbv & 7)) << 4));
            }
            __builtin_amdgcn_s_setprio(1);
            if (!vpath) {
                #pragma unroll
                for (int fm = 0; fm < 4; fm++)
                    #pragma unroll
                    for (int fn = 0; fn < 4; fn++)
                        acc[fm][fn] = __builtin_amdgcn_mfma_f32_16x16x32_bf16(
                            bf[fn], af[fm], acc[fm][fn], 0, 0, 0);
            } else {
                #pragma unroll
                for (int fm = 0; fm < 4; fm++)
                    #pragma unroll
                    for (int fn = 0; fn < 4; fn++)
                        acc[fm][fn] = __builtin_amdgcn_mfma_f32_16x16x32_bf16(
                            af[fm], bf[fn], acc[fm][fn], 0, 0, 0);
            }
            __builtin_amdgcn_s_setprio(0);
        }
        asm volatile("s_waitcnt vmcnt(0) lgkmcnt(0)" ::: "memory");
        __builtin_amdgcn_s_barrier();
    }

    const int n_base = bn + wn * 64;

    if constexpr (KIND == 1) {
        #pragma unroll
        for (int fn = 0; fn < 4; fn++) {
            const int n0 = n_base + fn * 16 + 4 * g;
            const f32x4 b4 = *(const f32x4*)(bias + n0);
            #pragma unroll
            for (int fm = 0; fm < 4; fm++) {
                const int t = bm + wm * 64 + fm * 16 + ln15;
                f32x4 o = acc[fm][fn] + b4;
                *(f32x4*)(oF + (size_t)t * 1024 + n0) = o;
            }
        }
    } else if (!vpath) {
        short* dst = (n_base < 1024) ? oQ : oK;
        #pragma unroll
        for (int fn = 0; fn < 4; fn++) {
            const int n0 = n_base + fn * 16 + 4 * g;
            const f32x4 b4 = *(const f32x4*)(bias + n0);
            const int nl = n0 & 1023;
            const int h = nl >> 6, d = nl & 63;
            #pragma unroll
            for (int fm = 0; fm < 4; fm++) {
                const int t = bm + wm * 64 + fm * 16 + ln15;
                const int b = t >> 11, s = t & 2047;
                short4v pk = { f2bf(acc[fm][fn][0] + b4[0]), f2bf(acc[fm][fn][1] + b4[1]),
                               f2bf(acc[fm][fn][2] + b4[2]), f2bf(acc[fm][fn][3] + b4[3]) };
                *(short4v*)(dst + ((size_t)(b * HH + h) * SS + s) * HDD + d) = pk;
            }
        }
    } else {
        // V: permuted-key Vt store: pos = g*16 + (fm&1)*4 + ((fm>>1)&1)*8 + r
        #pragma unroll
        for (int fn = 0; fn < 4; fn++) {
            const int nf = n_base + fn * 16 + ln15;   // 2048..3071
            const float bb = bias[nf];
            const int nl = nf - 2048;
            const int h = nl >> 6, d = nl & 63;
            #pragma unroll
            for (int fm = 0; fm < 4; fm++) {
                const int t0 = bm + wm * 64 + fm * 16 + 4 * g;
                const int b = t0 >> 11;
                const int sb = (t0 & 2047) & ~63;
                const int pos = g * 16 + (fm & 1) * 4 + ((fm >> 1) & 1) * 8;
                short4v pk = { f2bf(acc[fm][fn][0] + bb), f2bf(acc[fm][fn][1] + bb),
                               f2bf(acc[fm][fn][2] + bb), f2bf(acc[fm][fn][3] + bb) };
                *(short4v*)(oV + ((size_t)(b * HH + h) * HDD + d) * SS + sb + pos) = pk;
            }
        }
    }
}

// ---------------------------------------------------------------------------
// MFMA flash attention: 1 block = 4 waves = 128 q rows; 32 q per wave (2
// q-fragments sharing each K/V read). l accumulated on the MFMA pipe via a
// ones-operand MFMA (no per-tile adds, no final shuffle). Defer-max.
// ---------------------------------------------------------------------------
__global__ __launch_bounds__(256, 2) void attn_mfma_kernel(
    const short* __restrict__ Qh, const short* __restrict__ Kh,
    const short* __restrict__ Vt, short* __restrict__ yb)
{
    __shared__ short lds[16384];               // [2 buf][K 4096 | V 4096] shorts

    const int lane = threadIdx.x & 63;
    const int wid  = threadIdx.x >> 6;
    const int ln15 = lane & 15;
    const int g    = lane >> 4;

    // 512 blocks; XCD swizzle: each XCD gets 4 consecutive (b,h)
    const int bid  = ((int)blockIdx.x & 7) * 64 + ((int)blockIdx.x >> 3);
    const int bh   = bid >> 4;                 // b*16 + h
    const int qB   = (bid & 15) * 128;
    const int qW   = qB + wid * 32;

    const short* qbase = Qh + (size_t)bh * SS * HDD;
    const short* kbase = Kh + (size_t)bh * SS * HDD;
    const short* vtb   = Vt + (size_t)bh * HDD * SS;

    short8 qf[2][2];
    #pragma unroll
    for (int qg = 0; qg < 2; qg++)
        #pragma unroll
        for (int c = 0; c < 2; c++)
            qf[qg][c] = *(const short8*)(qbase +
                (size_t)(qW + qg * 16 + ln15) * HDD + c * 32 + g * 8);

    const short8 ones = { 0x3f80, 0x3f80, 0x3f80, 0x3f80,
                          0x3f80, 0x3f80, 0x3f80, 0x3f80 };

    const int sr = lane >> 3;
    const int cs = lane & 7;
    const int sc8 = (cs ^ sr) << 3;

    auto stage = [&](int b, int s0) {
        #pragma unroll
        for (int j = 0; j < 2; j++) {
            const int rr = wid * 16 + j * 8 + sr;
            GLD16(kbase + (size_t)(s0 + rr) * HDD + sc8,
                  &lds[b * 8192 + (wid * 16 + j * 8) * 64]);
            GLD16(vtb + (size_t)rr * SS + s0 + sc8,
                  &lds[b * 8192 + 4096 + (wid * 16 + j * 8) * 64]);
        }
    };

    f32x4 o[2][4], ol[2];
    #pragma unroll
    for (int qg = 0; qg < 2; qg++) {
        ol[qg] = (f32x4){0.f, 0.f, 0.f, 0.f};
        #pragma unroll
        for (int c = 0; c < 4; c++) o[qg][c] = (f32x4){0.f, 0.f, 0.f, 0.f};
    }
    float m[2] = { -1e30f, -1e30f };

    stage(0, 0);
    asm volatile("s_waitcnt vmcnt(0)" ::: "memory");
    __builtin_amdgcn_s_barrier();

    for (int t = 0; t < SS / 64; ++t) {
        const int cur = t & 1;
        if (t < SS / 64 - 1) stage(cur ^ 1, (t + 1) * 64);

        // ---- QK^T
        const char* kb = (const char*)lds + cur * 16384;
        short8 kf[4][2];
        #pragma unroll
        for (int kg = 0; kg < 4; kg++) {
            const int rk = kg * 16 + ln15;
            #pragma unroll
            for (int c = 0; c < 2; c++)
                kf[kg][c] = *(const short8*)(kb + rk * 128 +
                                             (((c * 4 + g) ^ (rk & 7)) << 4));
        }
        const f32x4 z = {0.f, 0.f, 0.f, 0.f};
        f32x4 s[4][2];
        __builtin_amdgcn_s_setprio(1);
        #pragma unroll
        for (int kg = 0; kg < 4; kg++)
            #pragma unroll
            for (int qg = 0; qg < 2; qg++) {
                s[kg][qg] = __builtin_amdgcn_mfma_f32_16x16x32_bf16(
                    kf[kg][0], qf[qg][0], z, 0, 0, 0);
                s[kg][qg] = __builtin_amdgcn_mfma_f32_16x16x32_bf16(
                    kf[kg][1], qf[qg][1], s[kg][qg], 0, 0, 0);
            }
        __builtin_amdgcn_s_setprio(0);

        // ---- softmax (lane-local; l on MFMA pipe)
        float pm[2];
        #pragma unroll
        for (int qg = 0; qg < 2; qg++) {
            const float t0 = fmax3(s[0][qg][0], s[0][qg][1], s[0][qg][2]);
            const float t1 = fmax3(s[0][qg][3], s[1][qg][0], s[1][qg][1]);
            const float t2 = fmax3(s[1][qg][2], s[1][qg][3], s[2][qg][0]);
            const float t3 = fmax3(s[2][qg][1], s[2][qg][2], s[2][qg][3]);
            const float t4 = fmax3(s[3][qg][0], s[3][qg][1], s[3][qg][2]);
            pm[qg] = fmaxf(fmax3(t0, t1, t2), fmax3(t3, t4, s[3][qg][3]));
        }
        if (__any((pm[0] > m[0] + 8.f) || (pm[1] > m[1] + 8.f))) {
            #pragma unroll
            for (int qg = 0; qg < 2; qg++) {
                float pmw = fmaxf(pm[qg], __shfl_xor(pm[qg], 16));
                pmw = fmaxf(pmw, __shfl_xor(pmw, 32));
                const float mn = fmaxf(m[qg], pmw);
                const float corr = fast_exp2(m[qg] - mn);
                ol[qg] *= corr;
                #pragma unroll
                for (int c = 0; c < 4; c++) o[qg][c] *= corr;
                m[qg] = mn;
            }
        }

        union { unsigned u[4]; short8 v; } P0[2], P1[2];
        #pragma unroll
        for (int qg = 0; qg < 2; qg++) {
            float p[16];
            #pragma unroll
            for (int kg = 0; kg < 4; kg++)
                #pragma unroll
                for (int r = 0; r < 4; r++)
                    p[kg * 4 + r] = fast_exp2(s[kg][qg][r] - m[qg]);
            P0[qg].u[0] = cvt_pk_bf16(p[0], p[1]);
            P0[qg].u[1] = cvt_pk_bf16(p[2], p[3]);
            P0[qg].u[2] = cvt_pk_bf16(p[4], p[5]);
            P0[qg].u[3] = cvt_pk_bf16(p[6], p[7]);
            P1[qg].u[0] = cvt_pk_bf16(p[8], p[9]);
            P1[qg].u[1] = cvt_pk_bf16(p[10], p[11]);
            P1[qg].u[2] = cvt_pk_bf16(p[12], p[13]);
            P1[qg].u[3] = cvt_pk_bf16(p[14], p[15]);
        }

        // ---- PV + l (permuted-key layout: one b128 per half-fragment)
        const char* vb = kb + 8192;
        __builtin_amdgcn_s_setprio(1);
        #pragma unroll
        for (int c = 0; c < 4; c++) {
            const int rv = c * 16 + ln15;
            const int sw = ln15 & 7;
            short8 vf0 = *(const short8*)(vb + rv * 128 + (((2 * g) ^ sw) << 4));
            short8 vf1 = *(const short8*)(vb + rv * 128 + (((2 * g + 1) ^ sw) << 4));
            #pragma unroll
            for (int qg = 0; qg < 2; qg++) {
                o[qg][c] = __builtin_amdgcn_mfma_f32_16x16x32_bf16(
                    vf0, P0[qg].v, o[qg][c], 0, 0, 0);
                o[qg][c] = __builtin_amdgcn_mfma_f32_16x16x32_bf16(
                    vf1, P1[qg].v, o[qg][c], 0, 0, 0);
            }
        }
        #pragma unroll
        for (int qg = 0; qg < 2; qg++) {
            ol[qg] = __builtin_amdgcn_mfma_f32_16x16x32_bf16(ones, P0[qg].v, ol[qg], 0, 0, 0);
            ol[qg] = __builtin_amdgcn_mfma_f32_16x16x32_bf16(ones, P1[qg].v, ol[qg], 0, 0, 0);
        }
        __builtin_amdgcn_s_setprio(0);

        asm volatile("s_waitcnt vmcnt(0) lgkmcnt(0)" ::: "memory");
        __builtin_amdgcn_s_barrier();
    }

    const int b = bh >> 4, h = bh & 15;
    #pragma unroll
    for (int qg = 0; qg < 2; qg++) {
        const float inv = 1.f / ol[qg][0];
        #pragma unroll
        for (int c = 0; c < 4; c++) o[qg][c] *= inv;

        // exclusive postprocess: y -= (y . v_norm) v_norm (v from permuted Vt)
        const int spos = qB + (wid >> 1) * 64 + (ln15 >> 2) * 16 + qg * 4 +
                         (wid & 1) * 8 + (ln15 & 3);
        float v4[4][4];
        float nv = 0.f, dv = 0.f;
        #pragma unroll
        for (int c = 0; c < 4; c++)
            #pragma unroll
            for (int r = 0; r < 4; r++) {
                const float vd = bf2f(vtb[(size_t)(c * 16 + 4 * g + r) * SS + spos]);
                v4[c][r] = vd;
                nv += vd * vd;
                dv += o[qg][c][r] * vd;
            }
        nv += __shfl_xor(nv, 16); nv += __shfl_xor(nv, 32);
        dv += __shfl_xor(dv, 16); dv += __shfl_xor(dv, 32);
        const float tpp = dv / (nv + 1e-12f);

        const int tok = b * SS + qW + qg * 16 + ln15;
        #pragma unroll
        for (int c = 0; c < 4; c++) {
            short4v pk = { f2bf(o[qg][c][0] - v4[c][0] * tpp),
                           f2bf(o[qg][c][1] - v4[c][1] * tpp),
                           f2bf(o[qg][c][2] - v4[c][2] * tpp),
                           f2bf(o[qg][c][3] - v4[c][3] * tpp) };
            *(short4v*)(yb + (size_t)tok * 1024 + h * 64 + c * 16 + 4 * g) = pk;
        }
    }
}

// ---------------------------------------------------------------------------
// Launch
// ---------------------------------------------------------------------------
extern "C" void kernel_launch(void* const* d_in, const int* in_sizes, int n_in,
                              void* d_out, int out_size, void* d_ws, size_t ws_size,
                              hipStream_t stream)
{
    const float* x  = (const float*)d_in[0];
    const float* Wq = (const float*)d_in[1];
    const float* bq = (const float*)d_in[2];
    const float* Wk = (const float*)d_in[3];
    const float* bk = (const float*)d_in[4];
    const float* Wv = (const float*)d_in[5];
    const float* bv = (const float*)d_in[6];
    const float* Wo = (const float*)d_in[7];
    const float* bo = (const float*)d_in[8];
    float* out = (float*)d_out;

    // ws: xb 8M | Wt 6M | Wot 2M | bcat | Qh 8M | Kh 8M | Vt 8M | yb 8M (~49 MB)
    char* w = (char*)d_ws;
    short* xb   = (short*)(w);
    short* Wt   = (short*)(w + (8ull << 20));    // [3072][1024] bf16 (Q|K|V)
    short* Wot  = (short*)(w + (14ull << 20));   // [1024][1024] bf16
    float* bcat = (float*)(w + (16ull << 20));   // [3072]
    short* Qh   = (short*)(w + (17ull << 20));
    short* Kh   = (short*)(w + (25ull << 20));
    short* Vt   = (short*)(w + (33ull << 20));
    short* yb   = (short*)(w + (41ull << 20));

    const float qscale = 0.125f * 1.44269504f;   // 1/sqrt(HD) * log2(e)
    dim3 blk(256);

    conv_x<<<2048, blk, 0, stream>>>(x, xb);
    conv_w4<<<dim3(16, 16, 4), blk, 0, stream>>>(Wq, Wk, Wv, Wo, Wt, Wot, qscale);
    conv_bias<<<12, blk, 0, stream>>>(bq, bk, bv, bcat, qscale);

    gemm_mfma<0><<<dim3(32, 24), blk, 0, stream>>>(xb, Wt, bcat,
                                                   Qh, Kh, Vt, nullptr);

    attn_mfma_kernel<<<dim3(512), blk, 0, stream>>>(Qh, Kh, Vt, yb);

    gemm_mfma<1><<<dim3(32, 8), blk, 0, stream>>>(yb, Wot, bo,
                                                  nullptr, nullptr, nullptr, out);
}

// Round 7
// 103.711 us; speedup vs baseline: 83.1886x; 1.0876x over previous
//
#include <hip/hip_runtime.h>

#define BB 2
#define SS 2048
#define DD 1024
#define HH 16
#define HDD 64

typedef __attribute__((ext_vector_type(4))) float f32x4;
typedef __attribute__((ext_vector_type(8))) short short8;
typedef __attribute__((ext_vector_type(4))) short short4v;

__device__ __forceinline__ short f2bf(float f) {
    union { float f; unsigned u; } a; a.f = f;
    unsigned r = a.u + 0x7fffu + ((a.u >> 16) & 1u);
    return (short)(r >> 16);
}
__device__ __forceinline__ float bf2f(short s) {
    union { unsigned u; float f; } a; a.u = ((unsigned)(unsigned short)s) << 16;
    return a.f;
}
__device__ __forceinline__ float fast_exp2(float x) {
    float r;
    asm("v_exp_f32 %0, %1\n\ts_nop 0" : "=v"(r) : "v"(x));
    return r;
}
__device__ __forceinline__ unsigned cvt_pk_bf16(float lo, float hi) {
    unsigned r;
    asm("v_cvt_pk_bf16_f32 %0, %1, %2" : "=v"(r) : "v"(lo), "v"(hi));
    return r;
}
__device__ __forceinline__ float fmax3(float a, float b, float c) {
    float r;
    asm("v_max3_f32 %0, %1, %2, %3" : "=v"(r) : "v"(a), "v"(b), "v"(c));
    return r;
}

#define GLD16(gp, lp) __builtin_amdgcn_global_load_lds( \
    (const __attribute__((address_space(1))) void*)(gp), \
    (__attribute__((address_space(3))) void*)(lp), 16, 0, 0)

// ---------------------------------------------------------------------------
// One convert kernel: z<4 -> weight transposes (Wq,Wk,Wv->Wt; Wo->Wot),
// z==4 -> x fp32 -> bf16.
// ---------------------------------------------------------------------------
__global__ __launch_bounds__(256) void conv_all(
    const float* __restrict__ x,
    const float* __restrict__ Wq, const float* __restrict__ Wk,
    const float* __restrict__ Wv, const float* __restrict__ Wo,
    short* __restrict__ xb, short* __restrict__ Wt, short* __restrict__ Wot,
    float qscale)
{
    const int z = blockIdx.z;
    if (z == 4) {
        const int id = blockIdx.x * 16 + blockIdx.y;          // 0..255
        const size_t base = (size_t)id * 16384 + threadIdx.x * 8;
        #pragma unroll
        for (int it = 0; it < 8; ++it) {
            const size_t i = base + (size_t)it * 2048;
            f32x4 a = *(const f32x4*)(x + i);
            f32x4 b = *(const f32x4*)(x + i + 4);
            short8 o;
            #pragma unroll
            for (int j = 0; j < 4; j++) { o[j] = f2bf(a[j]); o[j + 4] = f2bf(b[j]); }
            *(short8*)(xb + i) = o;
        }
        return;
    }
    __shared__ float t[64][65];
    const float* src = (z == 0) ? Wq : (z == 1) ? Wk : (z == 2) ? Wv : Wo;
    short* dst = (z < 3) ? (Wt + (size_t)z * 1048576) : Wot;
    const float scale = (z == 0) ? qscale : 1.f;

    const int tid = threadIdx.x;
    const int c = tid & 63, rg = tid >> 6;
    const int bi = blockIdx.x * 64, bj = blockIdx.y * 64;
    #pragma unroll
    for (int i = 0; i < 16; i++)
        t[rg * 16 + i][c] = src[(size_t)(bi + rg * 16 + i) * 1024 + bj + c];
    __syncthreads();
    #pragma unroll
    for (int i = 0; i < 16; i++)
        dst[(size_t)(bj + rg * 16 + i) * 1024 + bi + c] = f2bf(scale * t[c][rg * 16 + i]);
}

// ---------------------------------------------------------------------------
// bf16 MFMA GEMM, global_load_lds + dbuf, 128x128 tile, BK=64, hoisted addrs.
// KIND 0: fused QKV (Bt=[3072][1024]); by<16 -> Q/K epilogue, else V (permuted
//         Vt). Bias read directly from bq/bk/bv with qscale inline.
// KIND 1: out-proj, fp32 + bias (b0).
// ---------------------------------------------------------------------------
template<int KIND>
__global__ __launch_bounds__(256, 2) void gemm_mfma(
    const short* __restrict__ A, const short* __restrict__ Bt,
    const float* __restrict__ b0, const float* __restrict__ b1,
    const float* __restrict__ b2, float qscale,
    short* __restrict__ oQ, short* __restrict__ oK, short* __restrict__ oV,
    float* __restrict__ oF)
{
    __shared__ short lds[32768];          // 2 buf x (A 16KB | B 16KB)
    const int tid = threadIdx.x;
    const int lane = tid & 63;
    const int ln15 = lane & 15, g = lane >> 4;
    const int swl = ln15 & 7;
    const int wid = tid >> 6;
    const int wm = wid >> 1, wn = wid & 1;
    const int bm = blockIdx.x * 128;
    const int bn = blockIdx.y * 128;
    const bool vpath = (KIND == 0) && (blockIdx.y >= 16);

    f32x4 acc[4][4];
    #pragma unroll
    for (int i = 0; i < 4; i++)
        #pragma unroll
        for (int j = 0; j < 4; j++) acc[i][j] = (f32x4){0.f, 0.f, 0.f, 0.f};

    // --- staging: uniform k-advancing bases + fixed lane offsets
    const int sr = lane >> 3, cs = lane & 7;
    const int sc8 = (cs ^ sr) << 3;
    const int rb = wid * 8;
    const short* Ak = A;                  // uniform, += 64 per tile
    const short* Bk = Bt;
    int aoff[4], boff[4], adst[4];
    #pragma unroll
    for (int j = 0; j < 4; j++) {
        aoff[j] = (bm + rb + j * 32 + sr) * 1024 + sc8;
        boff[j] = (bn + rb + j * 32 + sr) * 1024 + sc8;
        adst[j] = (rb + j * 32) * 64;
    }

    auto stage = [&](int BUF) {
        #pragma unroll
        for (int j = 0; j < 4; j++) {
            GLD16(Ak + aoff[j], &lds[BUF * 16384 + adst[j]]);
            GLD16(Bk + boff[j], &lds[BUF * 16384 + 8192 + adst[j]]);
        }
        Ak += 64; Bk += 64;
    };

    // --- hoisted LDS read bases (bytes); imm adds: f*2048, BUF*32768
    const char* ldsc = (const char*)lds;
    int aB[2], bB[2];
    #pragma unroll
    for (int kk = 0; kk < 2; kk++) {
        aB[kk] = (wm * 64 + ln15) * 128 + ((((kk << 2) | g) ^ swl) << 4);
        bB[kk] = 16384 + (wn * 64 + ln15) * 128 + ((((kk << 2) | g) ^ swl) << 4);
    }

    auto tilec = [&](int BUF) {
        #pragma unroll
        for (int kk = 0; kk < 2; kk++) {
            short8 af[4], bf[4];
            #pragma unroll
            for (int f = 0; f < 4; f++) {
                af[f] = *(const short8*)(ldsc + BUF * 32768 + aB[kk] + f * 2048);
                bf[f] = *(const short8*)(ldsc + BUF * 32768 + bB[kk] + f * 2048);
            }
            if (!vpath) {
                #pragma unroll
                for (int fm = 0; fm < 4; fm++)
                    #pragma unroll
                    for (int fn = 0; fn < 4; fn++)
                        acc[fm][fn] = __builtin_amdgcn_mfma_f32_16x16x32_bf16(
                            bf[fn], af[fm], acc[fm][fn], 0, 0, 0);
            } else {
                #pragma unroll
                for (int fm = 0; fm < 4; fm++)
                    #pragma unroll
                    for (int fn = 0; fn < 4; fn++)
                        acc[fm][fn] = __builtin_amdgcn_mfma_f32_16x16x32_bf16(
                            af[fm], bf[fn], acc[fm][fn], 0, 0, 0);
            }
        }
    };

    stage(0);
    asm volatile("s_waitcnt vmcnt(0)" ::: "memory");
    __builtin_amdgcn_s_barrier();

    #pragma unroll 1
    for (int i = 0; i < 7; ++i) {
        stage(1);
        tilec(0);
        asm volatile("s_waitcnt vmcnt(0) lgkmcnt(0)" ::: "memory");
        __builtin_amdgcn_s_barrier();
        stage(0);
        tilec(1);
        asm volatile("s_waitcnt vmcnt(0) lgkmcnt(0)" ::: "memory");
        __builtin_amdgcn_s_barrier();
    }
    stage(1);
    tilec(0);
    asm volatile("s_waitcnt vmcnt(0) lgkmcnt(0)" ::: "memory");
    __builtin_amdgcn_s_barrier();
    tilec(1);

    const int n_base = bn + wn * 64;

    if constexpr (KIND == 1) {
        #pragma unroll
        for (int fn = 0; fn < 4; fn++) {
            const int n0 = n_base + fn * 16 + 4 * g;
            const f32x4 b4 = *(const f32x4*)(b0 + n0);
            #pragma unroll
            for (int fm = 0; fm < 4; fm++) {
                const int t = bm + wm * 64 + fm * 16 + ln15;
                f32x4 o = acc[fm][fn] + b4;
                *(f32x4*)(oF + (size_t)t * 1024 + n0) = o;
            }
        }
    } else if (!vpath) {
        const bool isq = (n_base < 1024);
        short* dst = isq ? oQ : oK;
        const float* bp = isq ? b0 : b1;
        const float scl = isq ? qscale : 1.f;
        #pragma unroll
        for (int fn = 0; fn < 4; fn++) {
            const int n0 = n_base + fn * 16 + 4 * g;
            const int nl = n0 & 1023;
            f32x4 b4 = *(const f32x4*)(bp + nl);
            b4 *= scl;
            const int h = nl >> 6, d = nl & 63;
            #pragma unroll
            for (int fm = 0; fm < 4; fm++) {
                const int t = bm + wm * 64 + fm * 16 + ln15;
                const int b = t >> 11, s = t & 2047;
                short4v pk = { f2bf(acc[fm][fn][0] + b4[0]), f2bf(acc[fm][fn][1] + b4[1]),
                               f2bf(acc[fm][fn][2] + b4[2]), f2bf(acc[fm][fn][3] + b4[3]) };
                *(short4v*)(dst + ((size_t)(b * HH + h) * SS + s) * HDD + d) = pk;
            }
        }
    } else {
        // V: permuted-key Vt store: pos = g*16 + (fm&1)*4 + ((fm>>1)&1)*8 + r
        #pragma unroll
        for (int fn = 0; fn < 4; fn++) {
            const int nf = n_base + fn * 16 + ln15;   // 2048..3071
            const int nl = nf - 2048;
            const float bb = b2[nl];
            const int h = nl >> 6, d = nl & 63;
            #pragma unroll
            for (int fm = 0; fm < 4; fm++) {
                const int t0 = bm + wm * 64 + fm * 16 + 4 * g;
                const int b = t0 >> 11;
                const int sb = (t0 & 2047) & ~63;
                const int pos = g * 16 + (fm & 1) * 4 + ((fm >> 1) & 1) * 8;
                short4v pk = { f2bf(acc[fm][fn][0] + bb), f2bf(acc[fm][fn][1] + bb),
                               f2bf(acc[fm][fn][2] + bb), f2bf(acc[fm][fn][3] + bb) };
                *(short4v*)(oV + ((size_t)(b * HH + h) * HDD + d) * SS + sb + pos) = pk;
            }
        }
    }
}

// ---------------------------------------------------------------------------
// MFMA flash attention: 4 waves x 32 q rows, KVBLK=64, LDS dbuf staging,
// hoisted lane-const swizzled addresses, unroll-2 (compile-time buffer),
// l on MFMA pipe, defer-max.
// ---------------------------------------------------------------------------
__global__ __launch_bounds__(256, 2) void attn_mfma_kernel(
    const short* __restrict__ Qh, const short* __restrict__ Kh,
    const short* __restrict__ Vt, short* __restrict__ yb)
{
    __shared__ short lds[16384];               // [2 buf][K 4096 | V 4096] shorts

    const int lane = threadIdx.x & 63;
    const int wid  = threadIdx.x >> 6;
    const int ln15 = lane & 15;
    const int g    = lane >> 4;
    const int swl  = ln15 & 7;

    const int bid  = ((int)blockIdx.x & 7) * 64 + ((int)blockIdx.x >> 3);
    const int bh   = bid >> 4;                 // b*16 + h
    const int qB   = (bid & 15) * 128;
    const int qW   = qB + wid * 32;

    const short* qbase = Qh + (size_t)bh * SS * HDD;
    const short* kbase = Kh + (size_t)bh * SS * HDD;
    const short* vtb   = Vt + (size_t)bh * HDD * SS;

    short8 qf[2][2];
    #pragma unroll
    for (int qg = 0; qg < 2; qg++)
        #pragma unroll
        for (int c = 0; c < 2; c++)
            qf[qg][c] = *(const short8*)(qbase +
                (size_t)(qW + qg * 16 + ln15) * HDD + c * 32 + g * 8);

    const short8 ones = { 0x3f80, 0x3f80, 0x3f80, 0x3f80,
                          0x3f80, 0x3f80, 0x3f80, 0x3f80 };

    // --- staging: uniform advancing bases + fixed lane offsets
    const int sr = lane >> 3;
    const int cs = lane & 7;
    const int sc8 = (cs ^ sr) << 3;
    const int r0 = wid * 16 + sr;
    const int r1 = wid * 16 + 8 + sr;
    const short* Kk = kbase;                   // += 4096 per tile (uniform)
    const short* Vk = vtb;                     // += 64 per tile (uniform)
    const int koff0 = r0 * 64 + sc8, koff1 = r1 * 64 + sc8;
    const int voff0 = r0 * 2048 + sc8, voff1 = r1 * 2048 + sc8;
    const int d0 = (wid * 16) * 64, d1 = (wid * 16 + 8) * 64;

    auto stage = [&](int BUF) {
        GLD16(Kk + koff0, &lds[BUF * 8192 + d0]);
        GLD16(Kk + koff1, &lds[BUF * 8192 + d1]);
        GLD16(Vk + voff0, &lds[BUF * 8192 + 4096 + d0]);
        GLD16(Vk + voff1, &lds[BUF * 8192 + 4096 + d1]);
        Kk += 4096; Vk += 64;
    };

    // --- hoisted LDS read bases (bytes); imm adds: kg/c*2048, BUF*16384
    const char* ldsc = (const char*)lds;
    const int kA0 = ln15 * 128 + ((g ^ swl) << 4);
    const int kA1 = ln15 * 128 + (((4 + g) ^ swl) << 4);
    const int vA0 = 8192 + ln15 * 128 + (((2 * g) ^ swl) << 4);
    const int vA1 = 8192 + ln15 * 128 + (((2 * g + 1) ^ swl) << 4);

    f32x4 o[2][4], ol[2];
    #pragma unroll
    for (int qg = 0; qg < 2; qg++) {
        ol[qg] = (f32x4){0.f, 0.f, 0.f, 0.f};
        #pragma unroll
        for (int c = 0; c < 4; c++) o[qg][c] = (f32x4){0.f, 0.f, 0.f, 0.f};
    }
    float m[2] = { -1e30f, -1e30f };

    auto tilec = [&](int BUF) {
        short8 kf[4][2];
        #pragma unroll
        for (int kg = 0; kg < 4; kg++) {
            kf[kg][0] = *(const short8*)(ldsc + BUF * 16384 + kA0 + kg * 2048);
            kf[kg][1] = *(const short8*)(ldsc + BUF * 16384 + kA1 + kg * 2048);
        }
        const f32x4 z = {0.f, 0.f, 0.f, 0.f};
        f32x4 s[4][2];
        __builtin_amdgcn_s_setprio(1);
        #pragma unroll
        for (int kg = 0; kg < 4; kg++)
            #pragma unroll
            for (int qg = 0; qg < 2; qg++) {
                s[kg][qg] = __builtin_amdgcn_mfma_f32_16x16x32_bf16(
                    kf[kg][0], qf[qg][0], z, 0, 0, 0);
                s[kg][qg] = __builtin_amdgcn_mfma_f32_16x16x32_bf16(
                    kf[kg][1], qf[qg][1], s[kg][qg], 0, 0, 0);
            }
        __builtin_amdgcn_s_setprio(0);

        float pm[2];
        #pragma unroll
        for (int qg = 0; qg < 2; qg++) {
            const float t0 = fmax3(s[0][qg][0], s[0][qg][1], s[0][qg][2]);
            const float t1 = fmax3(s[0][qg][3], s[1][qg][0], s[1][qg][1]);
            const float t2 = fmax3(s[1][qg][2], s[1][qg][3], s[2][qg][0]);
            const float t3 = fmax3(s[2][qg][1], s[2][qg][2], s[2][qg][3]);
            const float t4 = fmax3(s[3][qg][0], s[3][qg][1], s[3][qg][2]);
            pm[qg] = fmaxf(fmax3(t0, t1, t2), fmax3(t3, t4, s[3][qg][3]));
        }
        if (__any((pm[0] > m[0] + 8.f) || (pm[1] > m[1] + 8.f))) {
            #pragma unroll
            for (int qg = 0; qg < 2; qg++) {
                float pmw = fmaxf(pm[qg], __shfl_xor(pm[qg], 16));
                pmw = fmaxf(pmw, __shfl_xor(pmw, 32));
                const float mn = fmaxf(m[qg], pmw);
                const float corr = fast_exp2(m[qg] - mn);
                ol[qg] *= corr;
                #pragma unroll
                for (int c = 0; c < 4; c++) o[qg][c] *= corr;
                m[qg] = mn;
            }
        }

        union { unsigned u[4]; short8 v; } P0[2], P1[2];
        #pragma unroll
        for (int qg = 0; qg < 2; qg++) {
            float p[16];
            #pragma unroll
            for (int kg = 0; kg < 4; kg++)
                #pragma unroll
                for (int r = 0; r < 4; r++)
                    p[kg * 4 + r] = fast_exp2(s[kg][qg][r] - m[qg]);
            P0[qg].u[0] = cvt_pk_bf16(p[0], p[1]);
            P0[qg].u[1] = cvt_pk_bf16(p[2], p[3]);
            P0[qg].u[2] = cvt_pk_bf16(p[4], p[5]);
            P0[qg].u[3] = cvt_pk_bf16(p[6], p[7]);
            P1[qg].u[0] = cvt_pk_bf16(p[8], p[9]);
            P1[qg].u[1] = cvt_pk_bf16(p[10], p[11]);
            P1[qg].u[2] = cvt_pk_bf16(p[12], p[13]);
            P1[qg].u[3] = cvt_pk_bf16(p[14], p[15]);
        }

        __builtin_amdgcn_s_setprio(1);
        #pragma unroll
        for (int c = 0; c < 4; c++) {
            short8 vf0 = *(const short8*)(ldsc + BUF * 16384 + vA0 + c * 2048);
            short8 vf1 = *(const short8*)(ldsc + BUF * 16384 + vA1 + c * 2048);
            #pragma unroll
            for (int qg = 0; qg < 2; qg++) {
                o[qg][c] = __builtin_amdgcn_mfma_f32_16x16x32_bf16(
                    vf0, P0[qg].v, o[qg][c], 0, 0, 0);
                o[qg][c] = __builtin_amdgcn_mfma_f32_16x16x32_bf16(
                    vf1, P1[qg].v, o[qg][c], 0, 0, 0);
            }
        }
        #pragma unroll
        for (int qg = 0; qg < 2; qg++) {
            ol[qg] = __builtin_amdgcn_mfma_f32_16x16x32_bf16(ones, P0[qg].v, ol[qg], 0, 0, 0);
            ol[qg] = __builtin_amdgcn_mfma_f32_16x16x32_bf16(ones, P1[qg].v, ol[qg], 0, 0, 0);
        }
        __builtin_amdgcn_s_setprio(0);
    };

    stage(0);
    asm volatile("s_waitcnt vmcnt(0)" ::: "memory");
    __builtin_amdgcn_s_barrier();

    #pragma unroll 1
    for (int i = 0; i < 15; ++i) {
        stage(1);
        tilec(0);
        asm volatile("s_waitcnt vmcnt(0) lgkmcnt(0)" ::: "memory");
        __builtin_amdgcn_s_barrier();
        stage(0);
        tilec(1);
        asm volatile("s_waitcnt vmcnt(0) lgkmcnt(0)" ::: "memory");
        __builtin_amdgcn_s_barrier();
    }
    stage(1);
    tilec(0);
    asm volatile("s_waitcnt vmcnt(0) lgkmcnt(0)" ::: "memory");
    __builtin_amdgcn_s_barrier();
    tilec(1);

    const int b = bh >> 4, h = bh & 15;
    #pragma unroll
    for (int qg = 0; qg < 2; qg++) {
        const float inv = 1.f / ol[qg][0];
        #pragma unroll
        for (int c = 0; c < 4; c++) o[qg][c] *= inv;

        // exclusive postprocess: y -= (y . v_norm) v_norm (v from permuted Vt)
        const int spos = qB + (wid >> 1) * 64 + (ln15 >> 2) * 16 + qg * 4 +
                         (wid & 1) * 8 + (ln15 & 3);
        float v4[4][4];
        float nv = 0.f, dv = 0.f;
        #pragma unroll
        for (int c = 0; c < 4; c++)
            #pragma unroll
            for (int r = 0; r < 4; r++) {
                const float vd = bf2f(vtb[(size_t)(c * 16 + 4 * g + r) * SS + spos]);
                v4[c][r] = vd;
                nv += vd * vd;
                dv += o[qg][c][r] * vd;
            }
        nv += __shfl_xor(nv, 16); nv += __shfl_xor(nv, 32);
        dv += __shfl_xor(dv, 16); dv += __shfl_xor(dv, 32);
        const float tpp = dv / (nv + 1e-12f);

        const int tok = b * SS + qW + qg * 16 + ln15;
        #pragma unroll
        for (int c = 0; c < 4; c++) {
            short4v pk = { f2bf(o[qg][c][0] - v4[c][0] * tpp),
                           f2bf(o[qg][c][1] - v4[c][1] * tpp),
                           f2bf(o[qg][c][2] - v4[c][2] * tpp),
                           f2bf(o[qg][c][3] - v4[c][3] * tpp) };
            *(short4v*)(yb + (size_t)tok * 1024 + h * 64 + c * 16 + 4 * g) = pk;
        }
    }
}

// ---------------------------------------------------------------------------
// Launch
// ---------------------------------------------------------------------------
extern "C" void kernel_launch(void* const* d_in, const int* in_sizes, int n_in,
                              void* d_out, int out_size, void* d_ws, size_t ws_size,
                              hipStream_t stream)
{
    const float* x  = (const float*)d_in[0];
    const float* Wq = (const float*)d_in[1];
    const float* bq = (const float*)d_in[2];
    const float* Wk = (const float*)d_in[3];
    const float* bk = (const float*)d_in[4];
    const float* Wv = (const float*)d_in[5];
    const float* bv = (const float*)d_in[6];
    const float* Wo = (const float*)d_in[7];
    const float* bo = (const float*)d_in[8];
    float* out = (float*)d_out;

    // ws: xb 8M | Wt 6M | Wot 2M | Qh 8M | Kh 8M | Vt 8M | yb 8M (~48 MB)
    char* w = (char*)d_ws;
    short* xb   = (short*)(w);
    short* Wt   = (short*)(w + (8ull << 20));    // [3072][1024] bf16 (Q|K|V)
    short* Wot  = (short*)(w + (14ull << 20));   // [1024][1024] bf16
    short* Qh   = (short*)(w + (16ull << 20));
    short* Kh   = (short*)(w + (24ull << 20));
    short* Vt   = (short*)(w + (32ull << 20));
    short* yb   = (short*)(w + (40ull << 20));

    const float qscale = 0.125f * 1.44269504f;   // 1/sqrt(HD) * log2(e)
    dim3 blk(256);

    conv_all<<<dim3(16, 16, 5), blk, 0, stream>>>(x, Wq, Wk, Wv, Wo,
                                                  xb, Wt, Wot, qscale);

    gemm_mfma<0><<<dim3(32, 24), blk, 0, stream>>>(xb, Wt, bq, bk, bv, qscale,
                                                   Qh, Kh, Vt, nullptr);

    attn_mfma_kernel<<<dim3(512), blk, 0, stream>>>(Qh, Kh, Vt, yb);

    gemm_mfma<1><<<dim3(32, 8), blk, 0, stream>>>(yb, Wot, bo, nullptr, nullptr, 1.f,
                                                  nullptr, nullptr, nullptr, out);
}